// Round 7
// baseline (228.095 us; speedup 1.0000x reference)
//
#include <hip/hip_runtime.h>
#include <math.h>

#define NB 8
#define NC 512
#define NT 1024
#define BT (NB * NT)          // 8192 flattened (b,t) rows
#define SCALE 0.125f
#define NEG_BIG (-3.0e38f)

typedef __attribute__((ext_vector_type(8))) short short8v;   // 8 bf16 (A/B frag)
typedef __attribute__((ext_vector_type(8))) _Float16 half8v; // 8 fp16 (A/B frag)
typedef __attribute__((ext_vector_type(4))) float float4v;   // C/D frag
#define MFMA_BF16(A, B, C) __builtin_amdgcn_mfma_f32_16x16x32_bf16(A, B, C, 0, 0, 0)
#define MFMA_F16(A, B, C)  __builtin_amdgcn_mfma_f32_16x16x32_f16(A, B, C, 0, 0, 0)

__device__ __forceinline__ ushort f2bf(float f) {
    union { float f; unsigned int i; } v; v.f = f;
    unsigned int r = v.i + 0x7FFFu + ((v.i >> 16) & 1u);  // RNE
    return (ushort)(r >> 16);
}

__device__ __forceinline__ ushort f2h(float f) {
    return __builtin_bit_cast(unsigned short, (_Float16)f);
}

// P'(fp16) * row-scale, producing the f16 MFMA A-frag.
__device__ __forceinline__ half8v scale8(short8v raw, float s) {
    half8v h = __builtin_bit_cast(half8v, raw);
    const _Float16 hs = (_Float16)s;
    half8v r;
    #pragma unroll
    for (int q = 0; q < 8; ++q) r[q] = h[q] * hs;   // v_pk_mul_f16 x4
    return r;
}

#if defined(__has_builtin)
#if __has_builtin(__builtin_amdgcn_global_load_lds)
#define HAS_GLDS 1
#endif
#endif

#ifdef HAS_GLDS
__device__ __forceinline__ void glds16(const ushort* g, ushort* l) {
    __builtin_amdgcn_global_load_lds(
        (const __attribute__((address_space(1))) unsigned int*)g,
        (__attribute__((address_space(3))) unsigned int*)l, 16, 0, 0);
}
#endif

// ---------------------------------------------------------------------------
// BK=64 tile: ROWS x 64 shorts (128B rows). LDS slot p of row r holds global
// 16B-chunk p ^ (r&7)  => every ds_read_b128 frag phase is 2-way (free, m136).
// One issue = 64 lanes x 16B = 8 rows. 4 waves cover ROWS/8 issues.
// ---------------------------------------------------------------------------
template<int ROWS>
__device__ __forceinline__ void stage64(const ushort* __restrict__ g, int rsShorts,
                                        ushort* tile, int w, int lane) {
    const int r8 = lane >> 3;                  // row within 8-row group
    const int ck = (lane & 7) ^ r8;            // global chunk fetched by this lane
    const ushort* gl = g + (size_t)r8 * rsShorts + (ck << 3);
    constexpr int ni = ROWS / 32;              // issues per wave
    #pragma unroll
    for (int s = 0; s < ni; ++s) {
        const int issue = w * ni + s;
#ifdef HAS_GLDS
        glds16(gl + (size_t)issue * 8 * rsShorts, tile + issue * 512);
#else
        const uint4 v = *(const uint4*)(gl + (size_t)issue * 8 * rsShorts);
        *(uint4*)(tile + issue * 512 + lane * 8) = v;
#endif
    }
}

// frag read: row rr (local), chunk q (0..7): swizzled address
__device__ __forceinline__ short8v frag(const ushort* tile, int rr, int q) {
    return *(const short8v*)(tile + rr * 64 + ((q ^ (rr & 7)) << 3));
}

// XCD-chunk swizzle (T1, m157): nwg must be divisible by 8.
// Consecutive logical tiles land on the same XCD -> shared panels stay in L2.
__device__ __forceinline__ int xcd_swz(int flat, int cpx) {
    return (flat & 7) * cpx + (flat >> 3);
}

// ---------------------------------------------------------------------------
// prep_zw: merged prep. Blocks [0,2048): z fp32 [b][c][t] -> Z bf16
// token-major [comp][bt][c]. Blocks [2048,3072): 4x W fp32 -> bf16.
// ---------------------------------------------------------------------------
__global__ __launch_bounds__(256) void prep_zw_kernel(
    const float* __restrict__ zre, const float* __restrict__ zim,
    ushort* __restrict__ Z,
    const float* __restrict__ Wq, const float* __restrict__ Wk,
    const float* __restrict__ Wv, const float* __restrict__ Wo,
    ushort* __restrict__ Wbf)
{
    const int bx = blockIdx.x;
    const int tid = threadIdx.x;
    if (bx >= 2048) {                          // ---- prep_w part ----
        const int idx = (bx - 2048) * 256 + tid;
        const int e4 = idx << 2;
        const int m = e4 >> 18;
        const int off = e4 & ((1 << 18) - 1);
        const float* Ws[4] = {Wq, Wk, Wv, Wo};
        const float4 v = *(const float4*)(Ws[m] + off);
        ushort4 o;
        o.x = f2bf(v.x); o.y = f2bf(v.y); o.z = f2bf(v.z); o.w = f2bf(v.w);
        *(ushort4*)(Wbf + ((size_t)m << 18) + off) = o;
        return;
    }
    // ---- prep_z part ----
    const int t0 = (bx & 15) << 6, c0 = ((bx >> 4) & 7) << 6;
    const int bz = bx >> 7, b = bz & 7, comp = bz >> 3;
    const float* src = (comp ? zim : zre) + (size_t)b * NC * NT;
    ushort* dst = Z + (size_t)(comp * NB + b) * NT * NC;

    __shared__ ushort T[64][72];
    #pragma unroll
    for (int r = 0; r < 4; ++r) {
        const int cl = (tid >> 4) + r * 16;
        const int t4 = (tid & 15) << 2;
        const float4 v = *(const float4*)(src + (size_t)(c0 + cl) * NT + t0 + t4);
        T[t4 + 0][cl] = f2bf(v.x); T[t4 + 1][cl] = f2bf(v.y);
        T[t4 + 2][cl] = f2bf(v.z); T[t4 + 3][cl] = f2bf(v.w);
    }
    __syncthreads();
    const int tl = tid >> 2, cc = (tid & 3) << 4;
    ushort* op = dst + (size_t)(t0 + tl) * NC + c0 + cc;
    *(uint4*)op       = *(const uint4*)&T[tl][cc];
    *(uint4*)(op + 8) = *(const uint4*)&T[tl][cc + 8];
}

// ---------------------------------------------------------------------------
// proj_qk: tile 128(bt) x 64(d); wave 64x32 computes q AND k, re+im.
// XCD chunk = {8 m-tiles x all 8 d-bands}, d-fastest: Wq/Wk (1MB) L2-resident,
// each Z m-tile (0.5MB) fetched once, reused 8x from L2.
// Epilogue: LDS repack (re|im u32, stride 76) -> coalesced uint2 stores.
// ---------------------------------------------------------------------------
__global__ __launch_bounds__(256, 2) void proj_qk_kernel(
    const ushort* __restrict__ Z, const ushort* __restrict__ Wbf,
    const float* __restrict__ phiq, const float* __restrict__ phik,
    ushort* __restrict__ qre, ushort* __restrict__ qim,
    ushort* __restrict__ kre, ushort* __restrict__ kim)
{
    const int tid = threadIdx.x;
    // swizzle: grid (64, 8) = 512, cpx = 64; within chunk d0 fastest
    const int swz = xcd_swz(blockIdx.x + 64 * blockIdx.y, 64);
    const int d0 = (swz & 7) << 6;
    const int m0 = (swz >> 3) << 7;
    const size_t NE = (size_t)BT * NC;

    __shared__ alignas(16) ushort SM[24576];             // 48 KiB
    ushort* Zr   = SM;                                   // 128*64
    ushort* Zi   = SM + 8192;                            // 128*64
    ushort* Wq_s = SM + 16384;                           // 64*64
    ushort* Wk_s = SM + 20480;                           // 64*64
    uint*   R    = (uint*)SM;                            // repack [128][76]

    float4v accq[2][4][2] = {};
    float4v acck[2][4][2] = {};

    const int w = tid >> 6, lane = tid & 63;
    const int l15 = lane & 15, quad = lane >> 4;
    const int wm = (w & 1) << 6;
    const int wn = (w >> 1) << 5;

    for (int c0 = 0; c0 < NC; c0 += 64) {
        stage64<128>(Z + (size_t)m0 * NC + c0, NC, Zr, w, lane);
        stage64<128>(Z + NE + (size_t)m0 * NC + c0, NC, Zi, w, lane);
        stage64<64>(Wbf + (size_t)d0 * NC + c0, NC, Wq_s, w, lane);
        stage64<64>(Wbf + ((size_t)1 << 18) + (size_t)d0 * NC + c0, NC, Wk_s, w, lane);
        __syncthreads();
        #pragma unroll
        for (int kk = 0; kk < 2; ++kk) {
            const int q0 = kk * 4 + quad;
            short8v zf[2][4], wqf[2], wkf[2];
            #pragma unroll
            for (int i = 0; i < 4; ++i) {
                zf[0][i] = frag(Zr, wm + i * 16 + l15, q0);
                zf[1][i] = frag(Zi, wm + i * 16 + l15, q0);
            }
            #pragma unroll
            for (int j = 0; j < 2; ++j) {
                wqf[j] = frag(Wq_s, wn + j * 16 + l15, q0);
                wkf[j] = frag(Wk_s, wn + j * 16 + l15, q0);
            }
            #pragma unroll
            for (int c = 0; c < 2; ++c)
                #pragma unroll
                for (int i = 0; i < 4; ++i)
                    #pragma unroll
                    for (int j = 0; j < 2; ++j) {
                        accq[c][i][j] = MFMA_BF16(zf[c][i], wqf[j], accq[c][i][j]);
                        acck[c][i][j] = MFMA_BF16(zf[c][i], wkf[j], acck[c][i][j]);
                    }
        }
        __syncthreads();
    }

    // trig per j (2 d's per lane)
    float cq[2], sq[2], ck2[2], sk2[2];
    #pragma unroll
    for (int j = 0; j < 2; ++j) {
        const int d = d0 + wn + j * 16 + l15;
        const float pq = phiq[d], pk = phik[d];
        cq[j] = cosf(pq); sq[j] = sinf(pq);
        ck2[j] = cosf(pk); sk2[j] = sinf(pk);
    }
    const int g = tid >> 4, cl = tid & 15;

    // ---- round Q ----
    #pragma unroll
    for (int j = 0; j < 2; ++j)
        #pragma unroll
        for (int i = 0; i < 4; ++i)
            #pragma unroll
            for (int r = 0; r < 4; ++r) {
                const int row = wm + i * 16 + quad * 4 + r;
                const int col = wn + j * 16 + l15;
                const float ar = accq[0][i][j][r], ai = accq[1][i][j][r];
                R[row * 76 + col] = (uint)f2bf(ar * cq[j] - ai * sq[j])
                                  | ((uint)f2bf(ar * sq[j] + ai * cq[j]) << 16);
            }
    __syncthreads();
    #pragma unroll
    for (int s = 0; s < 8; ++s) {
        const int row = g * 8 + s;
        const uint4 p = *(const uint4*)&R[row * 76 + cl * 4];
        uint2 re, im;
        re.x = (p.x & 0xFFFFu) | (p.y << 16);
        re.y = (p.z & 0xFFFFu) | (p.w << 16);
        im.x = (p.x >> 16) | (p.y & 0xFFFF0000u);
        im.y = (p.z >> 16) | (p.w & 0xFFFF0000u);
        const size_t off = (size_t)(m0 + row) * NC + d0 + cl * 4;
        *(uint2*)(qre + off) = re;
        *(uint2*)(qim + off) = im;
    }
    __syncthreads();

    // ---- round K ----
    #pragma unroll
    for (int j = 0; j < 2; ++j)
        #pragma unroll
        for (int i = 0; i < 4; ++i)
            #pragma unroll
            for (int r = 0; r < 4; ++r) {
                const int row = wm + i * 16 + quad * 4 + r;
                const int col = wn + j * 16 + l15;
                const float br = acck[0][i][j][r], bi = acck[1][i][j][r];
                R[row * 76 + col] = (uint)f2bf(br * ck2[j] - bi * sk2[j])
                                  | ((uint)f2bf(br * sk2[j] + bi * ck2[j]) << 16);
            }
    __syncthreads();
    #pragma unroll
    for (int s = 0; s < 8; ++s) {
        const int row = g * 8 + s;
        const uint4 p = *(const uint4*)&R[row * 76 + cl * 4];
        uint2 re, im;
        re.x = (p.x & 0xFFFFu) | (p.y << 16);
        re.y = (p.z & 0xFFFFu) | (p.w << 16);
        im.x = (p.x >> 16) | (p.y & 0xFFFF0000u);
        im.y = (p.z >> 16) | (p.w & 0xFFFF0000u);
        const size_t off = (size_t)(m0 + row) * NC + d0 + cl * 4;
        *(uint2*)(kre + off) = re;
        *(uint2*)(kim + off) = im;
    }
}

// ---------------------------------------------------------------------------
// proj_v: tile 128(d) x 64(bt); A=Wv, B=Z -> channel-major v, re+im (FP16).
// Trig by shuffle; LDS-repack epilogue. Chunk order d-fastest.
// ---------------------------------------------------------------------------
__global__ __launch_bounds__(256, 3) void proj_v_kernel(
    const ushort* __restrict__ Z, const ushort* __restrict__ Wbf,
    const float* __restrict__ phiv,
    ushort* __restrict__ vre, ushort* __restrict__ vim)
{
    const int tid = threadIdx.x;
    // swizzle: grid (4, 128) = 512, cpx = 64
    const int swz = xcd_swz(blockIdx.x + 4 * blockIdx.y, 64);
    const int d0 = (swz & 3) << 7;
    const int bt0 = (swz >> 2) << 6;
    const size_t NE = (size_t)BT * NC;

    __shared__ alignas(16) ushort SM[19456];             // 38 KiB
    ushort* Wv_s = SM;                                   // 128*64
    ushort* Zr   = SM + 8192;                            // 64*64
    ushort* Zi   = SM + 12288;                           // 64*64
    uint*   R    = (uint*)SM;                            // repack [128][76]

    float4v acc[2][4][2] = {};

    const int w = tid >> 6, lane = tid & 63;
    const int l15 = lane & 15, quad = lane >> 4;
    const int wm = (w & 1) << 6;
    const int wn = (w >> 1) << 5;

    for (int c0 = 0; c0 < NC; c0 += 64) {
        stage64<128>(Wbf + ((size_t)2 << 18) + (size_t)d0 * NC + c0, NC, Wv_s, w, lane);
        stage64<64>(Z + (size_t)bt0 * NC + c0, NC, Zr, w, lane);
        stage64<64>(Z + NE + (size_t)bt0 * NC + c0, NC, Zi, w, lane);
        __syncthreads();
        #pragma unroll
        for (int kk = 0; kk < 2; ++kk) {
            const int q0 = kk * 4 + quad;
            short8v wvf[4], zf[2][2];
            #pragma unroll
            for (int i = 0; i < 4; ++i)
                wvf[i] = frag(Wv_s, wm + i * 16 + l15, q0);
            #pragma unroll
            for (int j = 0; j < 2; ++j) {
                zf[0][j] = frag(Zr, wn + j * 16 + l15, q0);
                zf[1][j] = frag(Zi, wn + j * 16 + l15, q0);
            }
            #pragma unroll
            for (int c = 0; c < 2; ++c)
                #pragma unroll
                for (int i = 0; i < 4; ++i)
                    #pragma unroll
                    for (int j = 0; j < 2; ++j)
                        acc[c][i][j] = MFMA_BF16(wvf[i], zf[c][j], acc[c][i][j]);
        }
        __syncthreads();
    }

    // trig: lane computes its own (i,r)=(l15>>2,l15&3), shuffle to distribute
    const int d_own = d0 + wm + (l15 >> 2) * 16 + quad * 4 + (l15 & 3);
    const float ph_own = phiv[d_own];
    const float c_own = cosf(ph_own), s_own = sinf(ph_own);

    #pragma unroll
    for (int i = 0; i < 4; ++i)
        #pragma unroll
        for (int r = 0; r < 4; ++r) {
            const int src = (lane & 48) | (i * 4 + r);
            const float cs = __shfl(c_own, src, 64);
            const float sn = __shfl(s_own, src, 64);
            const int row = wm + i * 16 + quad * 4 + r;      // d-local
            #pragma unroll
            for (int j = 0; j < 2; ++j) {
                const int col = wn + j * 16 + l15;           // t-local
                const float vr = acc[0][i][j][r], vi = acc[1][i][j][r];
                R[row * 76 + col] = (uint)f2h(vr * cs - vi * sn)
                                  | ((uint)f2h(vr * sn + vi * cs) << 16);
            }
        }
    __syncthreads();
    const int g = tid >> 4, cl = tid & 15;
    const int b = bt0 >> 10, t0 = bt0 & 1023;
    #pragma unroll
    for (int s = 0; s < 8; ++s) {
        const int row = g * 8 + s;
        const uint4 p = *(const uint4*)&R[row * 76 + cl * 4];
        uint2 re, im;
        re.x = (p.x & 0xFFFFu) | (p.y << 16);
        re.y = (p.z & 0xFFFFu) | (p.w << 16);
        im.x = (p.x >> 16) | (p.y & 0xFFFF0000u);
        im.y = (p.z >> 16) | (p.w & 0xFFFF0000u);
        const size_t off = (size_t)b * NC * NT + (size_t)(d0 + row) * NT + t0 + cl * 4;
        *(uint2*)(vre + off) = re;
        *(uint2*)(vim + off) = im;
    }
}

// ---------------------------------------------------------------------------
// scores: tile 128(t) x 128(u); heavy t-tiles first; re/im PHASE-SPLIT.
// Fused per-64u-subtile softmax -> P' fp16 via LDS repack + (m,l) stats.
// batch b pinned to XCD b (swizzle) => P'/stats stay in that XCD's L2 for pv.
// ---------------------------------------------------------------------------
__global__ __launch_bounds__(256, 3) void scores_kernel(
    const ushort* __restrict__ qre, const ushort* __restrict__ qim,
    const ushort* __restrict__ kre, const ushort* __restrict__ kim,
    ushort* __restrict__ Pp, float2* __restrict__ stats)
{
    // swizzle: grid (8, 8, 8) = 512, cpx = 64 -> one batch per XCD chunk
    const int swz = xcd_swz(blockIdx.x + 8 * (blockIdx.y + 8 * blockIdx.z), 64);
    const int u0b = (swz & 7) << 7;
    const int t0b = (7 - ((swz >> 3) & 7)) << 7;         // heavy first
    if (u0b > t0b) return;
    const int b = swz >> 6;
    const int tid = threadIdx.x;
    const size_t qb = (size_t)b * NT * NC;

    __shared__ alignas(16) ushort SM[17920];             // 35 KiB
    ushort* Qs = SM;             // 128*64
    ushort* Ks = SM + 8192;      // 128*64
    ushort* Rs = SM;             // repack [128][140] shorts = 35840B

    float4v acc[4][4] = {};

    const int w = tid >> 6, lane = tid & 63;
    const int l15 = lane & 15, quad = lane >> 4;
    const int wm = (w & 1) << 6;
    const int wn = (w >> 1) << 6;

    for (int c0 = 0; c0 < NC; c0 += 64) {
        // ---- phase RE ----
        stage64<128>(qre + qb + (size_t)t0b * NC + c0, NC, Qs, w, lane);
        stage64<128>(kre + qb + (size_t)u0b * NC + c0, NC, Ks, w, lane);
        __syncthreads();
        #pragma unroll
        for (int kk = 0; kk < 2; ++kk) {
            const int q0 = kk * 4 + quad;
            short8v qf[4], kf[4];
            #pragma unroll
            for (int i = 0; i < 4; ++i) {
                qf[i] = frag(Qs, wm + i * 16 + l15, q0);
                kf[i] = frag(Ks, wn + i * 16 + l15, q0);
            }
            #pragma unroll
            for (int i = 0; i < 4; ++i)
                #pragma unroll
                for (int j = 0; j < 4; ++j)
                    acc[i][j] = MFMA_BF16(qf[i], kf[j], acc[i][j]);
        }
        __syncthreads();
        // ---- phase IM (same buffers, accumulate) ----
        stage64<128>(qim + qb + (size_t)t0b * NC + c0, NC, Qs, w, lane);
        stage64<128>(kim + qb + (size_t)u0b * NC + c0, NC, Ks, w, lane);
        __syncthreads();
        #pragma unroll
        for (int kk = 0; kk < 2; ++kk) {
            const int q0 = kk * 4 + quad;
            short8v qf[4], kf[4];
            #pragma unroll
            for (int i = 0; i < 4; ++i) {
                qf[i] = frag(Qs, wm + i * 16 + l15, q0);
                kf[i] = frag(Ks, wn + i * 16 + l15, q0);
            }
            #pragma unroll
            for (int i = 0; i < 4; ++i)
                #pragma unroll
                for (int j = 0; j < 4; ++j)
                    acc[i][j] = MFMA_BF16(qf[i], kf[j], acc[i][j]);
        }
        __syncthreads();
    }

    // ---- fused per-64u-subtile softmax stats + P' into LDS repack ----
    const int sub = (u0b + wn) >> 6;            // global 64u-subtile index
    float2* st = stats + (size_t)(b * 16 + sub) * NT;
    #pragma unroll
    for (int i = 0; i < 4; ++i)
        #pragma unroll
        for (int r = 0; r < 4; ++r) {
            const int t = t0b + wm + i * 16 + quad * 4 + r;
            float v[4]; float m = NEG_BIG;
            #pragma unroll
            for (int j = 0; j < 4; ++j) {
                const int u = u0b + wn + j * 16 + l15;
                const float x = (u > t) ? NEG_BIG : acc[i][j][r] * SCALE;
                v[j] = x; m = fmaxf(m, x);
            }
            #pragma unroll
            for (int d = 1; d < 16; d <<= 1) m = fmaxf(m, __shfl_xor(m, d, 64));
            float l = 0.f;
            const int row = wm + i * 16 + quad * 4 + r;
            #pragma unroll
            for (int j = 0; j < 4; ++j) {
                const float e = __expf(v[j] - m);   // masked: exp(-3e38-m)=0
                l += e;
                Rs[row * 140 + wn + j * 16 + l15] = f2h(e);
            }
            #pragma unroll
            for (int d = 1; d < 16; d <<= 1) l += __shfl_xor(l, d, 64);
            if (l15 == 0) st[t] = make_float2(m, l);
            // fully-masked subtile: m=NEG_BIG, l=64, P'=1 -- harmless, its
            // pv scale exp(m-M)/L underflows to exactly 0.
        }
    __syncthreads();
    ushort* Pb = Pp + (size_t)b * NT * NT;
    const int g = tid >> 5, cl = tid & 31;
    #pragma unroll
    for (int s = 0; s < 16; ++s) {
        const int row = g * 16 + s;
        const uint2 p = *(const uint2*)&Rs[row * 140 + cl * 4];
        *(uint2*)(Pb + (size_t)(t0b + row) * NT + u0b + cl * 4) = p;
    }
}

// ---------------------------------------------------------------------------
// pv: tile 128(t) x 64(c); heavy t-tiles first; A=P' fp16 scaled by softmax
// scale, B=V fp16 channel-major. BARRIER-FREE main loop: P' (2MB/batch) and
// V (2MB/batch) are L2/L3-resident (P' written by scores on the SAME XCD via
// matching batch-per-XCD swizzle) -- read MFMA frags directly from global
// (16B-aligned b128 loads), no LDS staging, no vmcnt(0) drains (lesson m169).
// LDS holds only sLds (scales) and the repack buffer (aliased, barrier-fenced).
// ---------------------------------------------------------------------------
__global__ __launch_bounds__(256, 3) void pv_kernel(
    const ushort* __restrict__ Pp, const float2* __restrict__ stats,
    const ushort* __restrict__ vre, const ushort* __restrict__ vim,
    ushort* __restrict__ Ore, ushort* __restrict__ Oim)
{
    // swizzle: grid (8, 8, 8) = 512, cpx = 64 -> one batch per XCD chunk
    const int swz = xcd_swz(blockIdx.x + 8 * (blockIdx.y + 8 * blockIdx.z), 64);
    const int c0b = (swz & 7) << 6;
    const int t0b = (7 - ((swz >> 3) & 7)) << 7;         // heavy first
    const int b = swz >> 6;
    const int tid = threadIdx.x;
    const ushort* P  = Pp + ((size_t)b * NT + t0b) * NT;
    const ushort* Vr = vre + (size_t)b * NC * NT + (size_t)c0b * NT;
    const ushort* Vi = vim + (size_t)b * NC * NT + (size_t)c0b * NT;
    const int iters = (t0b + 128) >> 6;

    __shared__ alignas(16) uint SMu[128 * 76];           // 38 KiB repack
    float* sLds = (float*)SMu;                           // [128][17], aliased:
    uint*  R    = SMu;                                   // fenced by barriers

    float4v acc[2][4][2] = {};

    const int w = tid >> 6, lane = tid & 63;
    const int l15 = lane & 15, quad = lane >> 4;
    const int wm = (w & 1) << 6;
    const int wn = (w >> 1) << 5;

    // prologue: combine subtile stats -> scale_s = exp(m_s - M) / L
    if (tid < 128) {
        const int t = t0b + tid;
        float mv[16], lv[16];
        #pragma unroll
        for (int s = 0; s < 16; ++s) {
            if (s < iters) {
                const float2 v = stats[(size_t)(b * 16 + s) * NT + t];
                mv[s] = v.x; lv[s] = v.y;
            } else { mv[s] = NEG_BIG; lv[s] = 0.f; }
        }
        float M = NEG_BIG;
        #pragma unroll
        for (int s = 0; s < 16; ++s) M = fmaxf(M, mv[s]);
        float L = 0.f; float ev[16];
        #pragma unroll
        for (int s = 0; s < 16; ++s) { ev[s] = __expf(mv[s] - M); L += ev[s] * lv[s]; }
        const float inv = 1.0f / L;
        #pragma unroll
        for (int s = 0; s < 16; ++s) sLds[tid * 17 + s] = ev[s] * inv;
    }
    __syncthreads();                                     // sLds ready

    for (int it = 0; it < iters; ++it) {
        const int u0 = it << 6;
        #pragma unroll
        for (int kk = 0; kk < 2; ++kk) {
            const int co = u0 + (kk * 4 + quad) * 8;     // k-chunk this lane
            half8v pf[4], vfr[2], vfi[2];
            #pragma unroll
            for (int i = 0; i < 4; ++i) {
                const int row = wm + i * 16 + l15;       // t-local
                const short8v raw = *(const short8v*)(P + (size_t)row * NT + co);
                pf[i] = scale8(raw, sLds[row * 17 + it]);
            }
            #pragma unroll
            for (int j = 0; j < 2; ++j) {
                const int cr = wn + j * 16 + l15;        // c-local channel
                vfr[j] = *(const half8v*)(Vr + (size_t)cr * NT + co);
                vfi[j] = *(const half8v*)(Vi + (size_t)cr * NT + co);
            }
            #pragma unroll
            for (int i = 0; i < 4; ++i)
                #pragma unroll
                for (int j = 0; j < 2; ++j) {
                    acc[0][i][j] = MFMA_F16(pf[i], vfr[j], acc[0][i][j]);
                    acc[1][i][j] = MFMA_F16(pf[i], vfi[j], acc[1][i][j]);
                }
        }
    }

    __syncthreads();                                     // sLds dead -> reuse as R
    #pragma unroll
    for (int i = 0; i < 4; ++i)
        #pragma unroll
        for (int j = 0; j < 2; ++j)
            #pragma unroll
            for (int r = 0; r < 4; ++r) {
                const int row = wm + i * 16 + quad * 4 + r;   // t-local
                const int col = wn + j * 16 + l15;            // c-local
                R[row * 76 + col] = (uint)f2bf(acc[0][i][j][r])
                                  | ((uint)f2bf(acc[1][i][j][r]) << 16);
            }
    __syncthreads();
    const int g = tid >> 4, cl = tid & 15;
    #pragma unroll
    for (int s = 0; s < 8; ++s) {
        const int row = g * 8 + s;
        const uint4 p = *(const uint4*)&R[row * 76 + cl * 4];
        uint2 re, im;
        re.x = (p.x & 0xFFFFu) | (p.y << 16);
        re.y = (p.z & 0xFFFFu) | (p.w << 16);
        im.x = (p.x >> 16) | (p.y & 0xFFFF0000u);
        im.y = (p.z >> 16) | (p.w & 0xFFFF0000u);
        const size_t off = ((size_t)b * NT + t0b + row) * NC + c0b + cl * 4;
        *(uint2*)(Ore + off) = re;
        *(uint2*)(Oim + off) = im;
    }
}

// ---------------------------------------------------------------------------
// proj_out: tile 128(d) x 64(bt); A=Wo, B=O. fp32 -> d_out [b][d][t].
// Trig by shuffle; LDS-repack (fp32, two rounds) epilogue.
// ---------------------------------------------------------------------------
__global__ __launch_bounds__(256, 3) void proj_out_kernel(
    const ushort* __restrict__ Ore, const ushort* __restrict__ Oim,
    const ushort* __restrict__ Wbf, const float* __restrict__ phio,
    float* __restrict__ outRe, float* __restrict__ outIm)
{
    const int tid = threadIdx.x;
    // swizzle: grid (4, 128) = 512, cpx = 64
    const int swz = xcd_swz(blockIdx.x + 4 * blockIdx.y, 64);
    const int d0 = (swz & 3) << 7;
    const int bt0 = (swz >> 2) << 6;

    __shared__ alignas(16) ushort SM[19456];             // 38 KiB
    ushort* Wo_s = SM;                                   // 128*64
    ushort* Or_s = SM + 8192;                            // 64*64
    ushort* Oi_s = SM + 12288;                           // 64*64
    float*  Rf   = (float*)SM;                           // repack [128][76]

    float4v acc[2][4][2] = {};

    const int w = tid >> 6, lane = tid & 63;
    const int l15 = lane & 15, quad = lane >> 4;
    const int wm = (w & 1) << 6;
    const int wn = (w >> 1) << 5;

    for (int c0 = 0; c0 < NC; c0 += 64) {
        stage64<128>(Wbf + ((size_t)3 << 18) + (size_t)d0 * NC + c0, NC, Wo_s, w, lane);
        stage64<64>(Ore + (size_t)bt0 * NC + c0, NC, Or_s, w, lane);
        stage64<64>(Oim + (size_t)bt0 * NC + c0, NC, Oi_s, w, lane);
        __syncthreads();
        #pragma unroll
        for (int kk = 0; kk < 2; ++kk) {
            const int q0 = kk * 4 + quad;
            short8v wof[4], of[2][2];
            #pragma unroll
            for (int i = 0; i < 4; ++i)
                wof[i] = frag(Wo_s, wm + i * 16 + l15, q0);
            #pragma unroll
            for (int j = 0; j < 2; ++j) {
                of[0][j] = frag(Or_s, wn + j * 16 + l15, q0);
                of[1][j] = frag(Oi_s, wn + j * 16 + l15, q0);
            }
            #pragma unroll
            for (int c = 0; c < 2; ++c)
                #pragma unroll
                for (int i = 0; i < 4; ++i)
                    #pragma unroll
                    for (int j = 0; j < 2; ++j)
                        acc[c][i][j] = MFMA_BF16(wof[i], of[c][j], acc[c][i][j]);
        }
        __syncthreads();
    }

    // trig: one cosf/sinf per lane, shuffled to each (i,r)
    const int d_own = d0 + wm + (l15 >> 2) * 16 + quad * 4 + (l15 & 3);
    const float ph_own = phio[d_own];
    const float c_own = cosf(ph_own), s_own = sinf(ph_own);
    const int g = tid >> 4, cl = tid & 15;
    const int b = bt0 >> 10, t0 = bt0 & 1023;

    // ---- round RE ----
    #pragma unroll
    for (int i = 0; i < 4; ++i)
        #pragma unroll
        for (int r = 0; r < 4; ++r) {
            const int src = (lane & 48) | (i * 4 + r);
            const float cs = __shfl(c_own, src, 64);
            const float sn = __shfl(s_own, src, 64);
            const int row = wm + i * 16 + quad * 4 + r;
            #pragma unroll
            for (int j = 0; j < 2; ++j) {
                const int col = wn + j * 16 + l15;
                Rf[row * 76 + col] = acc[0][i][j][r] * cs - acc[1][i][j][r] * sn;
            }
        }
    __syncthreads();
    #pragma unroll
    for (int s = 0; s < 8; ++s) {
        const int row = g * 8 + s;
        const float4 p = *(const float4*)&Rf[row * 76 + cl * 4];
        *(float4*)(outRe + (size_t)b * NC * NT + (size_t)(d0 + row) * NT + t0 + cl * 4) = p;
    }
    __syncthreads();

    // ---- round IM ----
    #pragma unroll
    for (int i = 0; i < 4; ++i)
        #pragma unroll
        for (int r = 0; r < 4; ++r) {
            const int src = (lane & 48) | (i * 4 + r);
            const float cs = __shfl(c_own, src, 64);
            const float sn = __shfl(s_own, src, 64);
            const int row = wm + i * 16 + quad * 4 + r;
            #pragma unroll
            for (int j = 0; j < 2; ++j) {
                const int col = wn + j * 16 + l15;
                Rf[row * 76 + col] = acc[0][i][j][r] * sn + acc[1][i][j][r] * cs;
            }
        }
    __syncthreads();
    #pragma unroll
    for (int s = 0; s < 8; ++s) {
        const int row = g * 8 + s;
        const float4 p = *(const float4*)&Rf[row * 76 + cl * 4];
        *(float4*)(outIm + (size_t)b * NC * NT + (size_t)(d0 + row) * NT + t0 + cl * 4) = p;
    }
}

extern "C" void kernel_launch(void* const* d_in, const int* in_sizes, int n_in,
                              void* d_out, int out_size, void* d_ws, size_t ws_size,
                              hipStream_t stream) {
    (void)in_sizes; (void)n_in; (void)out_size; (void)ws_size;
    const float* z_re  = (const float*)d_in[0];
    const float* z_im  = (const float*)d_in[1];
    const float* Wq    = (const float*)d_in[2];
    const float* phi_q = (const float*)d_in[3];
    const float* Wk    = (const float*)d_in[4];
    const float* phi_k = (const float*)d_in[5];
    const float* Wv    = (const float*)d_in[6];
    const float* phi_v = (const float*)d_in[7];
    const float* Wo    = (const float*)d_in[8];
    const float* phi_o = (const float*)d_in[9];

    const size_t NE = (size_t)BT * NC;     // 4,194,304
    ushort* ws  = (ushort*)d_ws;
    ushort* qre = ws + 0 * NE; ushort* qim = ws + 1 * NE;   // aliased as O after scores
    ushort* kre = ws + 2 * NE; ushort* kim = ws + 3 * NE;
    ushort* vre = ws + 4 * NE; ushort* vim = ws + 5 * NE;   // channel-major fp16
    ushort* Wbf = ws + 6 * NE;                              // 2 MiB
    // d_out doubles as scratch:
    //   [0      , 16.8MB) : Z bf16 (dead after proj_qk/proj_v) -> stats (1MB)
    //   [16.8MB , 33.5MB) : P' fp16 (written by scores, read by pv)
    // proj_out finally overwrites all of d_out with outRe/outIm.
    ushort* Z  = (ushort*)d_out;
    ushort* Pp = (ushort*)d_out + 2 * NE;
    float2* stats = (float2*)d_out;        // 8 x 16 x 1024 float2 = 1 MiB

    const dim3 blk(256);
    hipLaunchKernelGGL(prep_zw_kernel, dim3(3072), blk, 0, stream,
                       z_re, z_im, Z, Wq, Wk, Wv, Wo, Wbf);
    hipLaunchKernelGGL(proj_qk_kernel, dim3(BT / 128, NC / 64), blk, 0, stream,
                       Z, Wbf, phi_q, phi_k, qre, qim, kre, kim);
    hipLaunchKernelGGL(proj_v_kernel, dim3(NC / 128, BT / 64), blk, 0, stream,
                       Z, Wbf, phi_v, vre, vim);
    hipLaunchKernelGGL(scores_kernel, dim3(NT / 128, NT / 128, NB), blk, 0, stream,
                       qre, qim, kre, kim, Pp, stats);
    hipLaunchKernelGGL(pv_kernel, dim3(NC / 64, NT / 128, NB), blk, 0, stream,
                       Pp, stats, vre, vim, qre, qim);
    hipLaunchKernelGGL(proj_out_kernel, dim3(NC / 128, BT / 64), blk, 0, stream,
                       qre, qim, Wbf, phi_o, (float*)d_out, (float*)d_out + NE);
}

// Round 9
// 198.063 us; speedup vs baseline: 1.1516x; 1.1516x over previous
//
#include <hip/hip_runtime.h>
#include <math.h>

#define NB 8
#define NC 512
#define NT 1024
#define BT (NB * NT)          // 8192 flattened (b,t) rows
#define SCALE 0.125f
#define NEG_BIG (-3.0e38f)

typedef __attribute__((ext_vector_type(8))) short short8v;   // 8 bf16 (A/B frag)
typedef __attribute__((ext_vector_type(8))) _Float16 half8v; // 8 fp16 (A/B frag)
typedef __attribute__((ext_vector_type(4))) float float4v;   // C/D frag
#define MFMA_BF16(A, B, C) __builtin_amdgcn_mfma_f32_16x16x32_bf16(A, B, C, 0, 0, 0)
#define MFMA_F16(A, B, C)  __builtin_amdgcn_mfma_f32_16x16x32_f16(A, B, C, 0, 0, 0)

__device__ __forceinline__ ushort f2bf(float f) {
    union { float f; unsigned int i; } v; v.f = f;
    unsigned int r = v.i + 0x7FFFu + ((v.i >> 16) & 1u);  // RNE
    return (ushort)(r >> 16);
}

__device__ __forceinline__ ushort f2h(float f) {
    return __builtin_bit_cast(unsigned short, (_Float16)f);
}

// P'(fp16, in LDS) * row-scale, producing the f16 MFMA A-frag.
__device__ __forceinline__ half8v scale8(short8v raw, float s) {
    half8v h = __builtin_bit_cast(half8v, raw);
    const _Float16 hs = (_Float16)s;
    half8v r;
    #pragma unroll
    for (int q = 0; q < 8; ++q) r[q] = h[q] * hs;   // v_pk_mul_f16 x4
    return r;
}

#if defined(__has_builtin)
#if __has_builtin(__builtin_amdgcn_global_load_lds)
#define HAS_GLDS 1
#endif
#endif

#ifdef HAS_GLDS
__device__ __forceinline__ void glds16(const ushort* g, ushort* l) {
    __builtin_amdgcn_global_load_lds(
        (const __attribute__((address_space(1))) unsigned int*)g,
        (__attribute__((address_space(3))) unsigned int*)l, 16, 0, 0);
}
#endif

// ---------------------------------------------------------------------------
// BK=64 tile: ROWS x 64 shorts (128B rows). LDS slot p of row r holds global
// 16B-chunk p ^ (r&7)  => every ds_read_b128 frag phase is 2-way (free, m136).
// One issue = 64 lanes x 16B = 8 rows. 4 waves cover ROWS/8 issues.
// ---------------------------------------------------------------------------
template<int ROWS>
__device__ __forceinline__ void stage64(const ushort* __restrict__ g, int rsShorts,
                                        ushort* tile, int w, int lane) {
    const int r8 = lane >> 3;                  // row within 8-row group
    const int ck = (lane & 7) ^ r8;            // global chunk fetched by this lane
    const ushort* gl = g + (size_t)r8 * rsShorts + (ck << 3);
    constexpr int ni = ROWS / 32;              // issues per wave
    #pragma unroll
    for (int s = 0; s < ni; ++s) {
        const int issue = w * ni + s;
#ifdef HAS_GLDS
        glds16(gl + (size_t)issue * 8 * rsShorts, tile + issue * 512);
#else
        const uint4 v = *(const uint4*)(gl + (size_t)issue * 8 * rsShorts);
        *(uint4*)(tile + issue * 512 + lane * 8) = v;
#endif
    }
}

// frag read: row rr (local), chunk q (0..7): swizzled address
__device__ __forceinline__ short8v frag(const ushort* tile, int rr, int q) {
    return *(const short8v*)(tile + rr * 64 + ((q ^ (rr & 7)) << 3));
}

// XCD-chunk swizzle (T1, m157): nwg must be divisible by 8.
// Consecutive logical tiles land on the same XCD -> shared panels stay in L2.
__device__ __forceinline__ int xcd_swz(int flat, int cpx) {
    return (flat & 7) * cpx + (flat >> 3);
}

// ---------------------------------------------------------------------------
// prep_zw: merged prep. Blocks [0,2048): z fp32 [b][c][t] -> Z bf16
// token-major [comp][bt][c]. Blocks [2048,3072): 4x W fp32 -> bf16.
// ---------------------------------------------------------------------------
__global__ __launch_bounds__(256) void prep_zw_kernel(
    const float* __restrict__ zre, const float* __restrict__ zim,
    ushort* __restrict__ Z,
    const float* __restrict__ Wq, const float* __restrict__ Wk,
    const float* __restrict__ Wv, const float* __restrict__ Wo,
    ushort* __restrict__ Wbf)
{
    const int bx = blockIdx.x;
    const int tid = threadIdx.x;
    if (bx >= 2048) {                          // ---- prep_w part ----
        const int idx = (bx - 2048) * 256 + tid;
        const int e4 = idx << 2;
        const int m = e4 >> 18;
        const int off = e4 & ((1 << 18) - 1);
        const float* Ws[4] = {Wq, Wk, Wv, Wo};
        const float4 v = *(const float4*)(Ws[m] + off);
        ushort4 o;
        o.x = f2bf(v.x); o.y = f2bf(v.y); o.z = f2bf(v.z); o.w = f2bf(v.w);
        *(ushort4*)(Wbf + ((size_t)m << 18) + off) = o;
        return;
    }
    // ---- prep_z part ----
    const int t0 = (bx & 15) << 6, c0 = ((bx >> 4) & 7) << 6;
    const int bz = bx >> 7, b = bz & 7, comp = bz >> 3;
    const float* src = (comp ? zim : zre) + (size_t)b * NC * NT;
    ushort* dst = Z + (size_t)(comp * NB + b) * NT * NC;

    __shared__ ushort T[64][72];
    #pragma unroll
    for (int r = 0; r < 4; ++r) {
        const int cl = (tid >> 4) + r * 16;
        const int t4 = (tid & 15) << 2;
        const float4 v = *(const float4*)(src + (size_t)(c0 + cl) * NT + t0 + t4);
        T[t4 + 0][cl] = f2bf(v.x); T[t4 + 1][cl] = f2bf(v.y);
        T[t4 + 2][cl] = f2bf(v.z); T[t4 + 3][cl] = f2bf(v.w);
    }
    __syncthreads();
    const int tl = tid >> 2, cc = (tid & 3) << 4;
    ushort* op = dst + (size_t)(t0 + tl) * NC + c0 + cc;
    *(uint4*)op       = *(const uint4*)&T[tl][cc];
    *(uint4*)(op + 8) = *(const uint4*)&T[tl][cc + 8];
}

// ---------------------------------------------------------------------------
// proj_qk: tile 128(bt) x 64(d); wave 64x32 computes q AND k, re+im.
// XCD chunk = {8 m-tiles x all 8 d-bands}, d-fastest: Wq/Wk (1MB) L2-resident,
// each Z m-tile (0.5MB) fetched once, reused 8x from L2.
// launch_bounds(256,3): 48KB LDS allows 3 blocks/CU.
// Epilogue: LDS repack (re|im u32, stride 76) -> coalesced uint2 stores.
// ---------------------------------------------------------------------------
__global__ __launch_bounds__(256, 3) void proj_qk_kernel(
    const ushort* __restrict__ Z, const ushort* __restrict__ Wbf,
    const float* __restrict__ phiq, const float* __restrict__ phik,
    ushort* __restrict__ qre, ushort* __restrict__ qim,
    ushort* __restrict__ kre, ushort* __restrict__ kim)
{
    const int tid = threadIdx.x;
    // swizzle: grid (64, 8) = 512, cpx = 64; within chunk d0 fastest
    const int swz = xcd_swz(blockIdx.x + 64 * blockIdx.y, 64);
    const int d0 = (swz & 7) << 6;
    const int m0 = (swz >> 3) << 7;
    const size_t NE = (size_t)BT * NC;

    __shared__ alignas(16) ushort SM[24576];             // 48 KiB
    ushort* Zr   = SM;                                   // 128*64
    ushort* Zi   = SM + 8192;                            // 128*64
    ushort* Wq_s = SM + 16384;                           // 64*64
    ushort* Wk_s = SM + 20480;                           // 64*64
    uint*   R    = (uint*)SM;                            // repack [128][76]

    float4v accq[2][4][2] = {};
    float4v acck[2][4][2] = {};

    const int w = tid >> 6, lane = tid & 63;
    const int l15 = lane & 15, quad = lane >> 4;
    const int wm = (w & 1) << 6;
    const int wn = (w >> 1) << 5;

    for (int c0 = 0; c0 < NC; c0 += 64) {
        stage64<128>(Z + (size_t)m0 * NC + c0, NC, Zr, w, lane);
        stage64<128>(Z + NE + (size_t)m0 * NC + c0, NC, Zi, w, lane);
        stage64<64>(Wbf + (size_t)d0 * NC + c0, NC, Wq_s, w, lane);
        stage64<64>(Wbf + ((size_t)1 << 18) + (size_t)d0 * NC + c0, NC, Wk_s, w, lane);
        __syncthreads();
        #pragma unroll
        for (int kk = 0; kk < 2; ++kk) {
            const int q0 = kk * 4 + quad;
            short8v zf[2][4], wqf[2], wkf[2];
            #pragma unroll
            for (int i = 0; i < 4; ++i) {
                zf[0][i] = frag(Zr, wm + i * 16 + l15, q0);
                zf[1][i] = frag(Zi, wm + i * 16 + l15, q0);
            }
            #pragma unroll
            for (int j = 0; j < 2; ++j) {
                wqf[j] = frag(Wq_s, wn + j * 16 + l15, q0);
                wkf[j] = frag(Wk_s, wn + j * 16 + l15, q0);
            }
            #pragma unroll
            for (int c = 0; c < 2; ++c)
                #pragma unroll
                for (int i = 0; i < 4; ++i)
                    #pragma unroll
                    for (int j = 0; j < 2; ++j) {
                        accq[c][i][j] = MFMA_BF16(zf[c][i], wqf[j], accq[c][i][j]);
                        acck[c][i][j] = MFMA_BF16(zf[c][i], wkf[j], acck[c][i][j]);
                    }
        }
        __syncthreads();
    }

    // trig per j (2 d's per lane)
    float cq[2], sq[2], ck2[2], sk2[2];
    #pragma unroll
    for (int j = 0; j < 2; ++j) {
        const int d = d0 + wn + j * 16 + l15;
        const float pq = phiq[d], pk = phik[d];
        cq[j] = cosf(pq); sq[j] = sinf(pq);
        ck2[j] = cosf(pk); sk2[j] = sinf(pk);
    }
    const int g = tid >> 4, cl = tid & 15;

    // ---- round Q ----
    #pragma unroll
    for (int j = 0; j < 2; ++j)
        #pragma unroll
        for (int i = 0; i < 4; ++i)
            #pragma unroll
            for (int r = 0; r < 4; ++r) {
                const int row = wm + i * 16 + quad * 4 + r;
                const int col = wn + j * 16 + l15;
                const float ar = accq[0][i][j][r], ai = accq[1][i][j][r];
                R[row * 76 + col] = (uint)f2bf(ar * cq[j] - ai * sq[j])
                                  | ((uint)f2bf(ar * sq[j] + ai * cq[j]) << 16);
            }
    __syncthreads();
    #pragma unroll
    for (int s = 0; s < 8; ++s) {
        const int row = g * 8 + s;
        const uint4 p = *(const uint4*)&R[row * 76 + cl * 4];
        uint2 re, im;
        re.x = (p.x & 0xFFFFu) | (p.y << 16);
        re.y = (p.z & 0xFFFFu) | (p.w << 16);
        im.x = (p.x >> 16) | (p.y & 0xFFFF0000u);
        im.y = (p.z >> 16) | (p.w & 0xFFFF0000u);
        const size_t off = (size_t)(m0 + row) * NC + d0 + cl * 4;
        *(uint2*)(qre + off) = re;
        *(uint2*)(qim + off) = im;
    }
    __syncthreads();

    // ---- round K ----
    #pragma unroll
    for (int j = 0; j < 2; ++j)
        #pragma unroll
        for (int i = 0; i < 4; ++i)
            #pragma unroll
            for (int r = 0; r < 4; ++r) {
                const int row = wm + i * 16 + quad * 4 + r;
                const int col = wn + j * 16 + l15;
                const float br = acck[0][i][j][r], bi = acck[1][i][j][r];
                R[row * 76 + col] = (uint)f2bf(br * ck2[j] - bi * sk2[j])
                                  | ((uint)f2bf(br * sk2[j] + bi * ck2[j]) << 16);
            }
    __syncthreads();
    #pragma unroll
    for (int s = 0; s < 8; ++s) {
        const int row = g * 8 + s;
        const uint4 p = *(const uint4*)&R[row * 76 + cl * 4];
        uint2 re, im;
        re.x = (p.x & 0xFFFFu) | (p.y << 16);
        re.y = (p.z & 0xFFFFu) | (p.w << 16);
        im.x = (p.x >> 16) | (p.y & 0xFFFF0000u);
        im.y = (p.z >> 16) | (p.w & 0xFFFF0000u);
        const size_t off = (size_t)(m0 + row) * NC + d0 + cl * 4;
        *(uint2*)(kre + off) = re;
        *(uint2*)(kim + off) = im;
    }
}

// ---------------------------------------------------------------------------
// proj_v: tile 128(d) x 64(bt); A=Wv, B=Z -> channel-major v, re+im (FP16).
// Trig by shuffle; LDS-repack epilogue. Chunk order d-fastest.
// ---------------------------------------------------------------------------
__global__ __launch_bounds__(256, 3) void proj_v_kernel(
    const ushort* __restrict__ Z, const ushort* __restrict__ Wbf,
    const float* __restrict__ phiv,
    ushort* __restrict__ vre, ushort* __restrict__ vim)
{
    const int tid = threadIdx.x;
    // swizzle: grid (4, 128) = 512, cpx = 64
    const int swz = xcd_swz(blockIdx.x + 4 * blockIdx.y, 64);
    const int d0 = (swz & 3) << 7;
    const int bt0 = (swz >> 2) << 6;
    const size_t NE = (size_t)BT * NC;

    __shared__ alignas(16) ushort SM[19456];             // 38 KiB
    ushort* Wv_s = SM;                                   // 128*64
    ushort* Zr   = SM + 8192;                            // 64*64
    ushort* Zi   = SM + 12288;                           // 64*64
    uint*   R    = (uint*)SM;                            // repack [128][76]

    float4v acc[2][4][2] = {};

    const int w = tid >> 6, lane = tid & 63;
    const int l15 = lane & 15, quad = lane >> 4;
    const int wm = (w & 1) << 6;
    const int wn = (w >> 1) << 5;

    for (int c0 = 0; c0 < NC; c0 += 64) {
        stage64<128>(Wbf + ((size_t)2 << 18) + (size_t)d0 * NC + c0, NC, Wv_s, w, lane);
        stage64<64>(Z + (size_t)bt0 * NC + c0, NC, Zr, w, lane);
        stage64<64>(Z + NE + (size_t)bt0 * NC + c0, NC, Zi, w, lane);
        __syncthreads();
        #pragma unroll
        for (int kk = 0; kk < 2; ++kk) {
            const int q0 = kk * 4 + quad;
            short8v wvf[4], zf[2][2];
            #pragma unroll
            for (int i = 0; i < 4; ++i)
                wvf[i] = frag(Wv_s, wm + i * 16 + l15, q0);
            #pragma unroll
            for (int j = 0; j < 2; ++j) {
                zf[0][j] = frag(Zr, wn + j * 16 + l15, q0);
                zf[1][j] = frag(Zi, wn + j * 16 + l15, q0);
            }
            #pragma unroll
            for (int c = 0; c < 2; ++c)
                #pragma unroll
                for (int i = 0; i < 4; ++i)
                    #pragma unroll
                    for (int j = 0; j < 2; ++j)
                        acc[c][i][j] = MFMA_BF16(wvf[i], zf[c][j], acc[c][i][j]);
        }
        __syncthreads();
    }

    // trig: lane computes its own (i,r)=(l15>>2,l15&3), shuffle to distribute
    const int d_own = d0 + wm + (l15 >> 2) * 16 + quad * 4 + (l15 & 3);
    const float ph_own = phiv[d_own];
    const float c_own = cosf(ph_own), s_own = sinf(ph_own);

    #pragma unroll
    for (int i = 0; i < 4; ++i)
        #pragma unroll
        for (int r = 0; r < 4; ++r) {
            const int src = (lane & 48) | (i * 4 + r);
            const float cs = __shfl(c_own, src, 64);
            const float sn = __shfl(s_own, src, 64);
            const int row = wm + i * 16 + quad * 4 + r;      // d-local
            #pragma unroll
            for (int j = 0; j < 2; ++j) {
                const int col = wn + j * 16 + l15;           // t-local
                const float vr = acc[0][i][j][r], vi = acc[1][i][j][r];
                R[row * 76 + col] = (uint)f2h(vr * cs - vi * sn)
                                  | ((uint)f2h(vr * sn + vi * cs) << 16);
            }
        }
    __syncthreads();
    const int g = tid >> 4, cl = tid & 15;
    const int b = bt0 >> 10, t0 = bt0 & 1023;
    #pragma unroll
    for (int s = 0; s < 8; ++s) {
        const int row = g * 8 + s;
        const uint4 p = *(const uint4*)&R[row * 76 + cl * 4];
        uint2 re, im;
        re.x = (p.x & 0xFFFFu) | (p.y << 16);
        re.y = (p.z & 0xFFFFu) | (p.w << 16);
        im.x = (p.x >> 16) | (p.y & 0xFFFF0000u);
        im.y = (p.z >> 16) | (p.w & 0xFFFF0000u);
        const size_t off = (size_t)b * NC * NT + (size_t)(d0 + row) * NT + t0 + cl * 4;
        *(uint2*)(vre + off) = re;
        *(uint2*)(vim + off) = im;
    }
}

// ---------------------------------------------------------------------------
// scores: tile 128(t) x 128(u); heavy t-tiles first; re/im PHASE-SPLIT:
// one 32KB Q/K buffer pair staged twice per K-step (re then im, accumulating)
// => LDS 35KB => 3 blocks/CU.
// Fused per-64u-subtile softmax -> P' fp16 via LDS repack + (m,l) stats.
// batch b pinned to XCD b (swizzle) => P'/stats stay in that XCD's L2 for pv.
// ---------------------------------------------------------------------------
__global__ __launch_bounds__(256, 3) void scores_kernel(
    const ushort* __restrict__ qre, const ushort* __restrict__ qim,
    const ushort* __restrict__ kre, const ushort* __restrict__ kim,
    ushort* __restrict__ Pp, float2* __restrict__ stats)
{
    // swizzle: grid (8, 8, 8) = 512, cpx = 64 -> one batch per XCD chunk
    const int swz = xcd_swz(blockIdx.x + 8 * (blockIdx.y + 8 * blockIdx.z), 64);
    const int u0b = (swz & 7) << 7;
    const int t0b = (7 - ((swz >> 3) & 7)) << 7;         // heavy first
    if (u0b > t0b) return;
    const int b = swz >> 6;
    const int tid = threadIdx.x;
    const size_t qb = (size_t)b * NT * NC;

    __shared__ alignas(16) ushort SM[17920];             // 35 KiB
    ushort* Qs = SM;             // 128*64
    ushort* Ks = SM + 8192;      // 128*64
    ushort* Rs = SM;             // repack [128][140] shorts = 35840B

    float4v acc[4][4] = {};

    const int w = tid >> 6, lane = tid & 63;
    const int l15 = lane & 15, quad = lane >> 4;
    const int wm = (w & 1) << 6;
    const int wn = (w >> 1) << 6;

    for (int c0 = 0; c0 < NC; c0 += 64) {
        // ---- phase RE ----
        stage64<128>(qre + qb + (size_t)t0b * NC + c0, NC, Qs, w, lane);
        stage64<128>(kre + qb + (size_t)u0b * NC + c0, NC, Ks, w, lane);
        __syncthreads();
        #pragma unroll
        for (int kk = 0; kk < 2; ++kk) {
            const int q0 = kk * 4 + quad;
            short8v qf[4], kf[4];
            #pragma unroll
            for (int i = 0; i < 4; ++i) {
                qf[i] = frag(Qs, wm + i * 16 + l15, q0);
                kf[i] = frag(Ks, wn + i * 16 + l15, q0);
            }
            #pragma unroll
            for (int i = 0; i < 4; ++i)
                #pragma unroll
                for (int j = 0; j < 4; ++j)
                    acc[i][j] = MFMA_BF16(qf[i], kf[j], acc[i][j]);
        }
        __syncthreads();
        // ---- phase IM (same buffers, accumulate) ----
        stage64<128>(qim + qb + (size_t)t0b * NC + c0, NC, Qs, w, lane);
        stage64<128>(kim + qb + (size_t)u0b * NC + c0, NC, Ks, w, lane);
        __syncthreads();
        #pragma unroll
        for (int kk = 0; kk < 2; ++kk) {
            const int q0 = kk * 4 + quad;
            short8v qf[4], kf[4];
            #pragma unroll
            for (int i = 0; i < 4; ++i) {
                qf[i] = frag(Qs, wm + i * 16 + l15, q0);
                kf[i] = frag(Ks, wn + i * 16 + l15, q0);
            }
            #pragma unroll
            for (int i = 0; i < 4; ++i)
                #pragma unroll
                for (int j = 0; j < 4; ++j)
                    acc[i][j] = MFMA_BF16(qf[i], kf[j], acc[i][j]);
        }
        __syncthreads();
    }

    // ---- fused per-64u-subtile softmax stats + P' into LDS repack ----
    const int sub = (u0b + wn) >> 6;            // global 64u-subtile index
    float2* st = stats + (size_t)(b * 16 + sub) * NT;
    #pragma unroll
    for (int i = 0; i < 4; ++i)
        #pragma unroll
        for (int r = 0; r < 4; ++r) {
            const int t = t0b + wm + i * 16 + quad * 4 + r;
            float v[4]; float m = NEG_BIG;
            #pragma unroll
            for (int j = 0; j < 4; ++j) {
                const int u = u0b + wn + j * 16 + l15;
                const float x = (u > t) ? NEG_BIG : acc[i][j][r] * SCALE;
                v[j] = x; m = fmaxf(m, x);
            }
            #pragma unroll
            for (int d = 1; d < 16; d <<= 1) m = fmaxf(m, __shfl_xor(m, d, 64));
            float l = 0.f;
            const int row = wm + i * 16 + quad * 4 + r;
            #pragma unroll
            for (int j = 0; j < 4; ++j) {
                const float e = __expf(v[j] - m);   // masked: exp(-3e38-m)=0
                l += e;
                Rs[row * 140 + wn + j * 16 + l15] = f2h(e);
            }
            #pragma unroll
            for (int d = 1; d < 16; d <<= 1) l += __shfl_xor(l, d, 64);
            if (l15 == 0) st[t] = make_float2(m, l);
            // fully-masked subtile: m=NEG_BIG, l=64, P'=1 -- harmless, its
            // pv scale exp(m-M)/L underflows to exactly 0.
        }
    __syncthreads();
    ushort* Pb = Pp + (size_t)b * NT * NT;
    const int g = tid >> 5, cl = tid & 31;
    #pragma unroll
    for (int s = 0; s < 16; ++s) {
        const int row = g * 16 + s;
        const uint2 p = *(const uint2*)&Rs[row * 140 + cl * 4];
        *(uint2*)(Pb + (size_t)(t0b + row) * NT + u0b + cl * 4) = p;
    }
}

// ---------------------------------------------------------------------------
// pv: tile 128(t) x 64(c); heavy t-tiles first; A=P' fp16 (scaled by
// per-(row,subtile) softmax scale from stats), B=V fp16 channel-major.
// LDS-staged main loop (round-6 form): direct-L2 frag reads measured 2x
// SLOWER (round 7: latency-bound at 12% occupancy) -- staging is load-bearing.
// ---------------------------------------------------------------------------
__global__ __launch_bounds__(256, 3) void pv_kernel(
    const ushort* __restrict__ Pp, const float2* __restrict__ stats,
    const ushort* __restrict__ vre, const ushort* __restrict__ vim,
    ushort* __restrict__ Ore, ushort* __restrict__ Oim)
{
    // swizzle: grid (8, 8, 8) = 512, cpx = 64 -> one batch per XCD chunk
    const int swz = xcd_swz(blockIdx.x + 8 * (blockIdx.y + 8 * blockIdx.z), 64);
    const int c0b = (swz & 7) << 6;
    const int t0b = (7 - ((swz >> 3) & 7)) << 7;         // heavy first
    const int b = swz >> 6;
    const int tid = threadIdx.x;
    const ushort* P = Pp + ((size_t)b * NT + t0b) * NT;
    const size_t vb = (size_t)b * NC * NT;
    const int iters = (t0b + 128) >> 6;

    __shared__ alignas(16) ushort SM[20736];             // 40.5 KiB
    ushort* Ps = SM;             // 128*64
    ushort* Vr = SM + 8192;      // 64*64
    ushort* Vi = SM + 12288;     // 64*64
    float* sLds = (float*)(SM + 16384);                  // [128][17]
    uint*  R    = (uint*)SM;                             // repack [128][76]

    float4v acc[2][4][2] = {};

    const int w = tid >> 6, lane = tid & 63;
    const int l15 = lane & 15, quad = lane >> 4;
    const int wm = (w & 1) << 6;
    const int wn = (w >> 1) << 5;

    // prologue: combine subtile stats -> scale_s = exp(m_s - M) / L
    if (tid < 128) {
        const int t = t0b + tid;
        float mv[16], lv[16];
        #pragma unroll
        for (int s = 0; s < 16; ++s) {
            if (s < iters) {
                const float2 v = stats[(size_t)(b * 16 + s) * NT + t];
                mv[s] = v.x; lv[s] = v.y;
            } else { mv[s] = NEG_BIG; lv[s] = 0.f; }
        }
        float M = NEG_BIG;
        #pragma unroll
        for (int s = 0; s < 16; ++s) M = fmaxf(M, mv[s]);
        float L = 0.f; float ev[16];
        #pragma unroll
        for (int s = 0; s < 16; ++s) { ev[s] = __expf(mv[s] - M); L += ev[s] * lv[s]; }
        const float inv = 1.0f / L;
        #pragma unroll
        for (int s = 0; s < 16; ++s) sLds[tid * 17 + s] = ev[s] * inv;
    }
    // visibility of sLds is covered by the first post-stage __syncthreads

    for (int it = 0; it < iters; ++it) {
        const int u0 = it << 6;
        stage64<128>(P + u0, NT, Ps, w, lane);
        stage64<64>(vre + vb + (size_t)c0b * NT + u0, NT, Vr, w, lane);
        stage64<64>(vim + vb + (size_t)c0b * NT + u0, NT, Vi, w, lane);
        __syncthreads();
        #pragma unroll
        for (int kk = 0; kk < 2; ++kk) {
            const int q0 = kk * 4 + quad;
            half8v pf[4], vf[2][2];
            #pragma unroll
            for (int i = 0; i < 4; ++i) {
                const int row = wm + i * 16 + l15;
                pf[i] = scale8(frag(Ps, row, q0), sLds[row * 17 + it]);
            }
            #pragma unroll
            for (int j = 0; j < 2; ++j) {
                vf[0][j] = __builtin_bit_cast(half8v, frag(Vr, wn + j * 16 + l15, q0));
                vf[1][j] = __builtin_bit_cast(half8v, frag(Vi, wn + j * 16 + l15, q0));
            }
            #pragma unroll
            for (int c = 0; c < 2; ++c)
                #pragma unroll
                for (int i = 0; i < 4; ++i)
                    #pragma unroll
                    for (int j = 0; j < 2; ++j)
                        acc[c][i][j] = MFMA_F16(pf[i], vf[c][j], acc[c][i][j]);
        }
        __syncthreads();
    }

    #pragma unroll
    for (int i = 0; i < 4; ++i)
        #pragma unroll
        for (int j = 0; j < 2; ++j)
            #pragma unroll
            for (int r = 0; r < 4; ++r) {
                const int row = wm + i * 16 + quad * 4 + r;   // t-local
                const int col = wn + j * 16 + l15;            // c-local
                R[row * 76 + col] = (uint)f2bf(acc[0][i][j][r])
                                  | ((uint)f2bf(acc[1][i][j][r]) << 16);
            }
    __syncthreads();
    const int g = tid >> 4, cl = tid & 15;
    #pragma unroll
    for (int s = 0; s < 8; ++s) {
        const int row = g * 8 + s;
        const uint4 p = *(const uint4*)&R[row * 76 + cl * 4];
        uint2 re, im;
        re.x = (p.x & 0xFFFFu) | (p.y << 16);
        re.y = (p.z & 0xFFFFu) | (p.w << 16);
        im.x = (p.x >> 16) | (p.y & 0xFFFF0000u);
        im.y = (p.z >> 16) | (p.w & 0xFFFF0000u);
        const size_t off = ((size_t)b * NT + t0b + row) * NC + c0b + cl * 4;
        *(uint2*)(Ore + off) = re;
        *(uint2*)(Oim + off) = im;
    }
}

// ---------------------------------------------------------------------------
// proj_out: tile 128(d) x 64(bt); A=Wo, B=O. fp32 -> d_out [b][d][t].
// Trig by shuffle; LDS-repack (fp32, two rounds) epilogue.
// ---------------------------------------------------------------------------
__global__ __launch_bounds__(256, 3) void proj_out_kernel(
    const ushort* __restrict__ Ore, const ushort* __restrict__ Oim,
    const ushort* __restrict__ Wbf, const float* __restrict__ phio,
    float* __restrict__ outRe, float* __restrict__ outIm)
{
    const int tid = threadIdx.x;
    // swizzle: grid (4, 128) = 512, cpx = 64
    const int swz = xcd_swz(blockIdx.x + 4 * blockIdx.y, 64);
    const int d0 = (swz & 3) << 7;
    const int bt0 = (swz >> 2) << 6;

    __shared__ alignas(16) ushort SM[19456];             // 38 KiB
    ushort* Wo_s = SM;                                   // 128*64
    ushort* Or_s = SM + 8192;                            // 64*64
    ushort* Oi_s = SM + 12288;                           // 64*64
    float*  Rf   = (float*)SM;                           // repack [128][76]

    float4v acc[2][4][2] = {};

    const int w = tid >> 6, lane = tid & 63;
    const int l15 = lane & 15, quad = lane >> 4;
    const int wm = (w & 1) << 6;
    const int wn = (w >> 1) << 5;

    for (int c0 = 0; c0 < NC; c0 += 64) {
        stage64<128>(Wbf + ((size_t)3 << 18) + (size_t)d0 * NC + c0, NC, Wo_s, w, lane);
        stage64<64>(Ore + (size_t)bt0 * NC + c0, NC, Or_s, w, lane);
        stage64<64>(Oim + (size_t)bt0 * NC + c0, NC, Oi_s, w, lane);
        __syncthreads();
        #pragma unroll
        for (int kk = 0; kk < 2; ++kk) {
            const int q0 = kk * 4 + quad;
            short8v wof[4], of[2][2];
            #pragma unroll
            for (int i = 0; i < 4; ++i)
                wof[i] = frag(Wo_s, wm + i * 16 + l15, q0);
            #pragma unroll
            for (int j = 0; j < 2; ++j) {
                of[0][j] = frag(Or_s, wn + j * 16 + l15, q0);
                of[1][j] = frag(Oi_s, wn + j * 16 + l15, q0);
            }
            #pragma unroll
            for (int c = 0; c < 2; ++c)
                #pragma unroll
                for (int i = 0; i < 4; ++i)
                    #pragma unroll
                    for (int j = 0; j < 2; ++j)
                        acc[c][i][j] = MFMA_BF16(wof[i], of[c][j], acc[c][i][j]);
        }
        __syncthreads();
    }

    // trig: one cosf/sinf per lane, shuffled to each (i,r)
    const int d_own = d0 + wm + (l15 >> 2) * 16 + quad * 4 + (l15 & 3);
    const float ph_own = phio[d_own];
    const float c_own = cosf(ph_own), s_own = sinf(ph_own);
    const int g = tid >> 4, cl = tid & 15;
    const int b = bt0 >> 10, t0 = bt0 & 1023;

    // ---- round RE ----
    #pragma unroll
    for (int i = 0; i < 4; ++i)
        #pragma unroll
        for (int r = 0; r < 4; ++r) {
            const int src = (lane & 48) | (i * 4 + r);
            const float cs = __shfl(c_own, src, 64);
            const float sn = __shfl(s_own, src, 64);
            const int row = wm + i * 16 + quad * 4 + r;
            #pragma unroll
            for (int j = 0; j < 2; ++j) {
                const int col = wn + j * 16 + l15;
                Rf[row * 76 + col] = acc[0][i][j][r] * cs - acc[1][i][j][r] * sn;
            }
        }
    __syncthreads();
    #pragma unroll
    for (int s = 0; s < 8; ++s) {
        const int row = g * 8 + s;
        const float4 p = *(const float4*)&Rf[row * 76 + cl * 4];
        *(float4*)(outRe + (size_t)b * NC * NT + (size_t)(d0 + row) * NT + t0 + cl * 4) = p;
    }
    __syncthreads();

    // ---- round IM ----
    #pragma unroll
    for (int i = 0; i < 4; ++i)
        #pragma unroll
        for (int r = 0; r < 4; ++r) {
            const int src = (lane & 48) | (i * 4 + r);
            const float cs = __shfl(c_own, src, 64);
            const float sn = __shfl(s_own, src, 64);
            const int row = wm + i * 16 + quad * 4 + r;
            #pragma unroll
            for (int j = 0; j < 2; ++j) {
                const int col = wn + j * 16 + l15;
                Rf[row * 76 + col] = acc[0][i][j][r] * sn + acc[1][i][j][r] * cs;
            }
        }
    __syncthreads();
    #pragma unroll
    for (int s = 0; s < 8; ++s) {
        const int row = g * 8 + s;
        const float4 p = *(const float4*)&Rf[row * 76 + cl * 4];
        *(float4*)(outIm + (size_t)b * NC * NT + (size_t)(d0 + row) * NT + t0 + cl * 4) = p;
    }
}

extern "C" void kernel_launch(void* const* d_in, const int* in_sizes, int n_in,
                              void* d_out, int out_size, void* d_ws, size_t ws_size,
                              hipStream_t stream) {
    (void)in_sizes; (void)n_in; (void)out_size; (void)ws_size;
    const float* z_re  = (const float*)d_in[0];
    const float* z_im  = (const float*)d_in[1];
    const float* Wq    = (const float*)d_in[2];
    const float* phi_q = (const float*)d_in[3];
    const float* Wk    = (const float*)d_in[4];
    const float* phi_k = (const float*)d_in[5];
    const float* Wv    = (const float*)d_in[6];
    const float* phi_v = (const float*)d_in[7];
    const float* Wo    = (const float*)d_in[8];
    const float* phi_o = (const float*)d_in[9];

    const size_t NE = (size_t)BT * NC;     // 4,194,304
    ushort* ws  = (ushort*)d_ws;
    ushort* qre = ws + 0 * NE; ushort* qim = ws + 1 * NE;   // aliased as O after scores
    ushort* kre = ws + 2 * NE; ushort* kim = ws + 3 * NE;
    ushort* vre = ws + 4 * NE; ushort* vim = ws + 5 * NE;   // channel-major fp16
    ushort* Wbf = ws + 6 * NE;                              // 2 MiB
    // d_out doubles as scratch:
    //   [0      , 16.8MB) : Z bf16 (dead after proj_qk/proj_v) -> stats (1MB)
    //   [16.8MB , 33.5MB) : P' fp16 (written by scores, read by pv)
    // proj_out finally overwrites all of d_out with outRe/outIm.
    ushort* Z  = (ushort*)d_out;
    ushort* Pp = (ushort*)d_out + 2 * NE;
    float2* stats = (float2*)d_out;        // 8 x 16 x 1024 float2 = 1 MiB

    const dim3 blk(256);
    hipLaunchKernelGGL(prep_zw_kernel, dim3(3072), blk, 0, stream,
                       z_re, z_im, Z, Wq, Wk, Wv, Wo, Wbf);
    hipLaunchKernelGGL(proj_qk_kernel, dim3(BT / 128, NC / 64), blk, 0, stream,
                       Z, Wbf, phi_q, phi_k, qre, qim, kre, kim);
    hipLaunchKernelGGL(proj_v_kernel, dim3(NC / 128, BT / 64), blk, 0, stream,
                       Z, Wbf, phi_v, vre, vim);
    hipLaunchKernelGGL(scores_kernel, dim3(NT / 128, NT / 128, NB), blk, 0, stream,
                       qre, qim, kre, kim, Pp, stats);
    hipLaunchKernelGGL(pv_kernel, dim3(NC / 64, NT / 128, NB), blk, 0, stream,
                       Pp, stats, vre, vim, qre, qim);
    hipLaunchKernelGGL(proj_out_kernel, dim3(NC / 128, BT / 64), blk, 0, stream,
                       qre, qim, Wbf, phi_o, (float*)d_out, (float*)d_out + NE);
}

// Round 10
// 195.565 us; speedup vs baseline: 1.1663x; 1.0128x over previous
//
#include <hip/hip_runtime.h>
#include <math.h>

#define NB 8
#define NC 512
#define NT 1024
#define BT (NB * NT)          // 8192 flattened (b,t) rows
#define SCALE 0.125f
#define NEG_BIG (-3.0e38f)

typedef __attribute__((ext_vector_type(8))) short short8v;   // 8 bf16 (A/B frag)
typedef __attribute__((ext_vector_type(8))) _Float16 half8v; // 8 fp16 (A/B frag)
typedef __attribute__((ext_vector_type(4))) float float4v;   // C/D frag
#define MFMA_BF16(A, B, C) __builtin_amdgcn_mfma_f32_16x16x32_bf16(A, B, C, 0, 0, 0)
#define MFMA_F16(A, B, C)  __builtin_amdgcn_mfma_f32_16x16x32_f16(A, B, C, 0, 0, 0)

__device__ __forceinline__ ushort f2bf(float f) {
    union { float f; unsigned int i; } v; v.f = f;
    unsigned int r = v.i + 0x7FFFu + ((v.i >> 16) & 1u);  // RNE
    return (ushort)(r >> 16);
}

__device__ __forceinline__ ushort f2h(float f) {
    return __builtin_bit_cast(unsigned short, (_Float16)f);
}

// P'(fp16, in LDS) * row-scale, producing the f16 MFMA A-frag.
__device__ __forceinline__ half8v scale8(short8v raw, float s) {
    half8v h = __builtin_bit_cast(half8v, raw);
    const _Float16 hs = (_Float16)s;
    half8v r;
    #pragma unroll
    for (int q = 0; q < 8; ++q) r[q] = h[q] * hs;   // v_pk_mul_f16 x4
    return r;
}

#if defined(__has_builtin)
#if __has_builtin(__builtin_amdgcn_global_load_lds)
#define HAS_GLDS 1
#endif
#endif

#ifdef HAS_GLDS
__device__ __forceinline__ void glds16(const ushort* g, ushort* l) {
    __builtin_amdgcn_global_load_lds(
        (const __attribute__((address_space(1))) unsigned int*)g,
        (__attribute__((address_space(3))) unsigned int*)l, 16, 0, 0);
}
#endif

// ---------------------------------------------------------------------------
// BK=64 tile: ROWS x 64 shorts (128B rows). LDS slot p of row r holds global
// 16B-chunk p ^ (r&7)  => every ds_read_b128 frag phase is 2-way (free, m136).
// One issue = 64 lanes x 16B = 8 rows. 4 waves cover ROWS/8 issues.
// ---------------------------------------------------------------------------
template<int ROWS>
__device__ __forceinline__ void stage64(const ushort* __restrict__ g, int rsShorts,
                                        ushort* tile, int w, int lane) {
    const int r8 = lane >> 3;                  // row within 8-row group
    const int ck = (lane & 7) ^ r8;            // global chunk fetched by this lane
    const ushort* gl = g + (size_t)r8 * rsShorts + (ck << 3);
    constexpr int ni = ROWS / 32;              // issues per wave
    #pragma unroll
    for (int s = 0; s < ni; ++s) {
        const int issue = w * ni + s;
#ifdef HAS_GLDS
        glds16(gl + (size_t)issue * 8 * rsShorts, tile + issue * 512);
#else
        const uint4 v = *(const uint4*)(gl + (size_t)issue * 8 * rsShorts);
        *(uint4*)(tile + issue * 512 + lane * 8) = v;
#endif
    }
}

// frag read: row rr (local), chunk q (0..7): swizzled address
__device__ __forceinline__ short8v frag(const ushort* tile, int rr, int q) {
    return *(const short8v*)(tile + rr * 64 + ((q ^ (rr & 7)) << 3));
}

// XCD-chunk swizzle (T1, m157): nwg must be divisible by 8.
// Consecutive logical tiles land on the same XCD -> shared panels stay in L2.
__device__ __forceinline__ int xcd_swz(int flat, int cpx) {
    return (flat & 7) * cpx + (flat >> 3);
}

// ---------------------------------------------------------------------------
// prep_zw: merged prep. Blocks [0,2048): z fp32 [b][c][t] -> Z bf16
// token-major [comp][bt][c]. Blocks [2048,3072): 4x W fp32 -> bf16.
// ---------------------------------------------------------------------------
__global__ __launch_bounds__(256) void prep_zw_kernel(
    const float* __restrict__ zre, const float* __restrict__ zim,
    ushort* __restrict__ Z,
    const float* __restrict__ Wq, const float* __restrict__ Wk,
    const float* __restrict__ Wv, const float* __restrict__ Wo,
    ushort* __restrict__ Wbf)
{
    const int bx = blockIdx.x;
    const int tid = threadIdx.x;
    if (bx >= 2048) {                          // ---- prep_w part ----
        const int idx = (bx - 2048) * 256 + tid;
        const int e4 = idx << 2;
        const int m = e4 >> 18;
        const int off = e4 & ((1 << 18) - 1);
        const float* Ws[4] = {Wq, Wk, Wv, Wo};
        const float4 v = *(const float4*)(Ws[m] + off);
        ushort4 o;
        o.x = f2bf(v.x); o.y = f2bf(v.y); o.z = f2bf(v.z); o.w = f2bf(v.w);
        *(ushort4*)(Wbf + ((size_t)m << 18) + off) = o;
        return;
    }
    // ---- prep_z part ----
    const int t0 = (bx & 15) << 6, c0 = ((bx >> 4) & 7) << 6;
    const int bz = bx >> 7, b = bz & 7, comp = bz >> 3;
    const float* src = (comp ? zim : zre) + (size_t)b * NC * NT;
    ushort* dst = Z + (size_t)(comp * NB + b) * NT * NC;

    __shared__ ushort T[64][72];
    #pragma unroll
    for (int r = 0; r < 4; ++r) {
        const int cl = (tid >> 4) + r * 16;
        const int t4 = (tid & 15) << 2;
        const float4 v = *(const float4*)(src + (size_t)(c0 + cl) * NT + t0 + t4);
        T[t4 + 0][cl] = f2bf(v.x); T[t4 + 1][cl] = f2bf(v.y);
        T[t4 + 2][cl] = f2bf(v.z); T[t4 + 3][cl] = f2bf(v.w);
    }
    __syncthreads();
    const int tl = tid >> 2, cc = (tid & 3) << 4;
    ushort* op = dst + (size_t)(t0 + tl) * NC + c0 + cc;
    *(uint4*)op       = *(const uint4*)&T[tl][cc];
    *(uint4*)(op + 8) = *(const uint4*)&T[tl][cc + 8];
}

// ---------------------------------------------------------------------------
// proj_qk: tile 128(bt) x 64(d); wave 64x32 computes q AND k, re+im.
// XCD chunk = {8 m-tiles x all 8 d-bands}, d-fastest: Wq/Wk (1MB) L2-resident,
// each Z m-tile (0.5MB) fetched once, reused 8x from L2.
// launch_bounds(256,2): (256,3) forced VGPR to 84 < 128 acc floats -> spill
// (round 9: 130us dispatch). 2 blocks/CU is the correct occupancy here.
// Epilogue: LDS repack (re|im u32, stride 76) -> coalesced uint2 stores.
// ---------------------------------------------------------------------------
__global__ __launch_bounds__(256, 2) void proj_qk_kernel(
    const ushort* __restrict__ Z, const ushort* __restrict__ Wbf,
    const float* __restrict__ phiq, const float* __restrict__ phik,
    ushort* __restrict__ qre, ushort* __restrict__ qim,
    ushort* __restrict__ kre, ushort* __restrict__ kim)
{
    const int tid = threadIdx.x;
    // swizzle: grid (64, 8) = 512, cpx = 64; within chunk d0 fastest
    const int swz = xcd_swz(blockIdx.x + 64 * blockIdx.y, 64);
    const int d0 = (swz & 7) << 6;
    const int m0 = (swz >> 3) << 7;
    const size_t NE = (size_t)BT * NC;

    __shared__ alignas(16) ushort SM[24576];             // 48 KiB
    ushort* Zr   = SM;                                   // 128*64
    ushort* Zi   = SM + 8192;                            // 128*64
    ushort* Wq_s = SM + 16384;                           // 64*64
    ushort* Wk_s = SM + 20480;                           // 64*64
    uint*   R    = (uint*)SM;                            // repack [128][76]

    float4v accq[2][4][2] = {};
    float4v acck[2][4][2] = {};

    const int w = tid >> 6, lane = tid & 63;
    const int l15 = lane & 15, quad = lane >> 4;
    const int wm = (w & 1) << 6;
    const int wn = (w >> 1) << 5;

    for (int c0 = 0; c0 < NC; c0 += 64) {
        stage64<128>(Z + (size_t)m0 * NC + c0, NC, Zr, w, lane);
        stage64<128>(Z + NE + (size_t)m0 * NC + c0, NC, Zi, w, lane);
        stage64<64>(Wbf + (size_t)d0 * NC + c0, NC, Wq_s, w, lane);
        stage64<64>(Wbf + ((size_t)1 << 18) + (size_t)d0 * NC + c0, NC, Wk_s, w, lane);
        __syncthreads();
        #pragma unroll
        for (int kk = 0; kk < 2; ++kk) {
            const int q0 = kk * 4 + quad;
            short8v zf[2][4], wqf[2], wkf[2];
            #pragma unroll
            for (int i = 0; i < 4; ++i) {
                zf[0][i] = frag(Zr, wm + i * 16 + l15, q0);
                zf[1][i] = frag(Zi, wm + i * 16 + l15, q0);
            }
            #pragma unroll
            for (int j = 0; j < 2; ++j) {
                wqf[j] = frag(Wq_s, wn + j * 16 + l15, q0);
                wkf[j] = frag(Wk_s, wn + j * 16 + l15, q0);
            }
            #pragma unroll
            for (int c = 0; c < 2; ++c)
                #pragma unroll
                for (int i = 0; i < 4; ++i)
                    #pragma unroll
                    for (int j = 0; j < 2; ++j) {
                        accq[c][i][j] = MFMA_BF16(zf[c][i], wqf[j], accq[c][i][j]);
                        acck[c][i][j] = MFMA_BF16(zf[c][i], wkf[j], acck[c][i][j]);
                    }
        }
        __syncthreads();
    }

    // trig per j (2 d's per lane)
    float cq[2], sq[2], ck2[2], sk2[2];
    #pragma unroll
    for (int j = 0; j < 2; ++j) {
        const int d = d0 + wn + j * 16 + l15;
        const float pq = phiq[d], pk = phik[d];
        cq[j] = cosf(pq); sq[j] = sinf(pq);
        ck2[j] = cosf(pk); sk2[j] = sinf(pk);
    }
    const int g = tid >> 4, cl = tid & 15;

    // ---- round Q ----
    #pragma unroll
    for (int j = 0; j < 2; ++j)
        #pragma unroll
        for (int i = 0; i < 4; ++i)
            #pragma unroll
            for (int r = 0; r < 4; ++r) {
                const int row = wm + i * 16 + quad * 4 + r;
                const int col = wn + j * 16 + l15;
                const float ar = accq[0][i][j][r], ai = accq[1][i][j][r];
                R[row * 76 + col] = (uint)f2bf(ar * cq[j] - ai * sq[j])
                                  | ((uint)f2bf(ar * sq[j] + ai * cq[j]) << 16);
            }
    __syncthreads();
    #pragma unroll
    for (int s = 0; s < 8; ++s) {
        const int row = g * 8 + s;
        const uint4 p = *(const uint4*)&R[row * 76 + cl * 4];
        uint2 re, im;
        re.x = (p.x & 0xFFFFu) | (p.y << 16);
        re.y = (p.z & 0xFFFFu) | (p.w << 16);
        im.x = (p.x >> 16) | (p.y & 0xFFFF0000u);
        im.y = (p.z >> 16) | (p.w & 0xFFFF0000u);
        const size_t off = (size_t)(m0 + row) * NC + d0 + cl * 4;
        *(uint2*)(qre + off) = re;
        *(uint2*)(qim + off) = im;
    }
    __syncthreads();

    // ---- round K ----
    #pragma unroll
    for (int j = 0; j < 2; ++j)
        #pragma unroll
        for (int i = 0; i < 4; ++i)
            #pragma unroll
            for (int r = 0; r < 4; ++r) {
                const int row = wm + i * 16 + quad * 4 + r;
                const int col = wn + j * 16 + l15;
                const float br = acck[0][i][j][r], bi = acck[1][i][j][r];
                R[row * 76 + col] = (uint)f2bf(br * ck2[j] - bi * sk2[j])
                                  | ((uint)f2bf(br * sk2[j] + bi * ck2[j]) << 16);
            }
    __syncthreads();
    #pragma unroll
    for (int s = 0; s < 8; ++s) {
        const int row = g * 8 + s;
        const uint4 p = *(const uint4*)&R[row * 76 + cl * 4];
        uint2 re, im;
        re.x = (p.x & 0xFFFFu) | (p.y << 16);
        re.y = (p.z & 0xFFFFu) | (p.w << 16);
        im.x = (p.x >> 16) | (p.y & 0xFFFF0000u);
        im.y = (p.z >> 16) | (p.w & 0xFFFF0000u);
        const size_t off = (size_t)(m0 + row) * NC + d0 + cl * 4;
        *(uint2*)(kre + off) = re;
        *(uint2*)(kim + off) = im;
    }
}

// ---------------------------------------------------------------------------
// proj_v: tile 128(d) x 64(bt); A=Wv, B=Z -> channel-major v, re+im (FP16).
// Trig by shuffle; LDS-repack epilogue. Chunk order d-fastest.
// ---------------------------------------------------------------------------
__global__ __launch_bounds__(256, 3) void proj_v_kernel(
    const ushort* __restrict__ Z, const ushort* __restrict__ Wbf,
    const float* __restrict__ phiv,
    ushort* __restrict__ vre, ushort* __restrict__ vim)
{
    const int tid = threadIdx.x;
    // swizzle: grid (4, 128) = 512, cpx = 64
    const int swz = xcd_swz(blockIdx.x + 4 * blockIdx.y, 64);
    const int d0 = (swz & 3) << 7;
    const int bt0 = (swz >> 2) << 6;
    const size_t NE = (size_t)BT * NC;

    __shared__ alignas(16) ushort SM[19456];             // 38 KiB
    ushort* Wv_s = SM;                                   // 128*64
    ushort* Zr   = SM + 8192;                            // 64*64
    ushort* Zi   = SM + 12288;                           // 64*64
    uint*   R    = (uint*)SM;                            // repack [128][76]

    float4v acc[2][4][2] = {};

    const int w = tid >> 6, lane = tid & 63;
    const int l15 = lane & 15, quad = lane >> 4;
    const int wm = (w & 1) << 6;
    const int wn = (w >> 1) << 5;

    for (int c0 = 0; c0 < NC; c0 += 64) {
        stage64<128>(Wbf + ((size_t)2 << 18) + (size_t)d0 * NC + c0, NC, Wv_s, w, lane);
        stage64<64>(Z + (size_t)bt0 * NC + c0, NC, Zr, w, lane);
        stage64<64>(Z + NE + (size_t)bt0 * NC + c0, NC, Zi, w, lane);
        __syncthreads();
        #pragma unroll
        for (int kk = 0; kk < 2; ++kk) {
            const int q0 = kk * 4 + quad;
            short8v wvf[4], zf[2][2];
            #pragma unroll
            for (int i = 0; i < 4; ++i)
                wvf[i] = frag(Wv_s, wm + i * 16 + l15, q0);
            #pragma unroll
            for (int j = 0; j < 2; ++j) {
                zf[0][j] = frag(Zr, wn + j * 16 + l15, q0);
                zf[1][j] = frag(Zi, wn + j * 16 + l15, q0);
            }
            #pragma unroll
            for (int c = 0; c < 2; ++c)
                #pragma unroll
                for (int i = 0; i < 4; ++i)
                    #pragma unroll
                    for (int j = 0; j < 2; ++j)
                        acc[c][i][j] = MFMA_BF16(wvf[i], zf[c][j], acc[c][i][j]);
        }
        __syncthreads();
    }

    // trig: lane computes its own (i,r)=(l15>>2,l15&3), shuffle to distribute
    const int d_own = d0 + wm + (l15 >> 2) * 16 + quad * 4 + (l15 & 3);
    const float ph_own = phiv[d_own];
    const float c_own = cosf(ph_own), s_own = sinf(ph_own);

    #pragma unroll
    for (int i = 0; i < 4; ++i)
        #pragma unroll
        for (int r = 0; r < 4; ++r) {
            const int src = (lane & 48) | (i * 4 + r);
            const float cs = __shfl(c_own, src, 64);
            const float sn = __shfl(s_own, src, 64);
            const int row = wm + i * 16 + quad * 4 + r;      // d-local
            #pragma unroll
            for (int j = 0; j < 2; ++j) {
                const int col = wn + j * 16 + l15;           // t-local
                const float vr = acc[0][i][j][r], vi = acc[1][i][j][r];
                R[row * 76 + col] = (uint)f2h(vr * cs - vi * sn)
                                  | ((uint)f2h(vr * sn + vi * cs) << 16);
            }
        }
    __syncthreads();
    const int g = tid >> 4, cl = tid & 15;
    const int b = bt0 >> 10, t0 = bt0 & 1023;
    #pragma unroll
    for (int s = 0; s < 8; ++s) {
        const int row = g * 8 + s;
        const uint4 p = *(const uint4*)&R[row * 76 + cl * 4];
        uint2 re, im;
        re.x = (p.x & 0xFFFFu) | (p.y << 16);
        re.y = (p.z & 0xFFFFu) | (p.w << 16);
        im.x = (p.x >> 16) | (p.y & 0xFFFF0000u);
        im.y = (p.z >> 16) | (p.w & 0xFFFF0000u);
        const size_t off = (size_t)b * NC * NT + (size_t)(d0 + row) * NT + t0 + cl * 4;
        *(uint2*)(vre + off) = re;
        *(uint2*)(vim + off) = im;
    }
}

// ---------------------------------------------------------------------------
// scores: tile 128(t) x 128(u); heavy t-tiles first; SINGLE-STAGE 64KB form:
// all four Q/K re+im tiles resident => 2 barriers + 32 MFMA/wave per K-step
// (the round-5 re/im phase-split doubled barrier drains for +1 block/CU --
// barrier-exposure arithmetic says that trade loses; this round isolates it).
// Fused per-64u-subtile softmax -> P' fp16 via LDS repack + (m,l) stats.
// batch b pinned to XCD b (swizzle) => P'/stats stay in that XCD's L2 for pv.
// ---------------------------------------------------------------------------
__global__ __launch_bounds__(256, 2) void scores_kernel(
    const ushort* __restrict__ qre, const ushort* __restrict__ qim,
    const ushort* __restrict__ kre, const ushort* __restrict__ kim,
    ushort* __restrict__ Pp, float2* __restrict__ stats)
{
    // swizzle: grid (8, 8, 8) = 512, cpx = 64 -> one batch per XCD chunk
    const int swz = xcd_swz(blockIdx.x + 8 * (blockIdx.y + 8 * blockIdx.z), 64);
    const int u0b = (swz & 7) << 7;
    const int t0b = (7 - ((swz >> 3) & 7)) << 7;         // heavy first
    if (u0b > t0b) return;
    const int b = swz >> 6;
    const int tid = threadIdx.x;
    const size_t qb = (size_t)b * NT * NC;

    __shared__ alignas(16) ushort SM[32768];             // 64 KiB
    ushort* Qr = SM;             // 128*64
    ushort* Qi = SM + 8192;
    ushort* Kr = SM + 16384;
    ushort* Ki = SM + 24576;
    ushort* Rs = SM;             // repack [128][140] shorts = 35840B

    float4v acc[4][4] = {};

    const int w = tid >> 6, lane = tid & 63;
    const int l15 = lane & 15, quad = lane >> 4;
    const int wm = (w & 1) << 6;
    const int wn = (w >> 1) << 6;

    for (int c0 = 0; c0 < NC; c0 += 64) {
        stage64<128>(qre + qb + (size_t)t0b * NC + c0, NC, Qr, w, lane);
        stage64<128>(qim + qb + (size_t)t0b * NC + c0, NC, Qi, w, lane);
        stage64<128>(kre + qb + (size_t)u0b * NC + c0, NC, Kr, w, lane);
        stage64<128>(kim + qb + (size_t)u0b * NC + c0, NC, Ki, w, lane);
        __syncthreads();
        #pragma unroll
        for (int kk = 0; kk < 2; ++kk) {
            const int q0 = kk * 4 + quad;
            short8v qf[2][4], kf[2][4];
            #pragma unroll
            for (int i = 0; i < 4; ++i) {
                qf[0][i] = frag(Qr, wm + i * 16 + l15, q0);
                qf[1][i] = frag(Qi, wm + i * 16 + l15, q0);
                kf[0][i] = frag(Kr, wn + i * 16 + l15, q0);
                kf[1][i] = frag(Ki, wn + i * 16 + l15, q0);
            }
            #pragma unroll
            for (int i = 0; i < 4; ++i)
                #pragma unroll
                for (int j = 0; j < 4; ++j) {
                    acc[i][j] = MFMA_BF16(qf[0][i], kf[0][j], acc[i][j]);
                    acc[i][j] = MFMA_BF16(qf[1][i], kf[1][j], acc[i][j]);
                }
        }
        __syncthreads();
    }

    // ---- fused per-64u-subtile softmax stats + P' into LDS repack ----
    const int sub = (u0b + wn) >> 6;            // global 64u-subtile index
    float2* st = stats + (size_t)(b * 16 + sub) * NT;
    #pragma unroll
    for (int i = 0; i < 4; ++i)
        #pragma unroll
        for (int r = 0; r < 4; ++r) {
            const int t = t0b + wm + i * 16 + quad * 4 + r;
            float v[4]; float m = NEG_BIG;
            #pragma unroll
            for (int j = 0; j < 4; ++j) {
                const int u = u0b + wn + j * 16 + l15;
                const float x = (u > t) ? NEG_BIG : acc[i][j][r] * SCALE;
                v[j] = x; m = fmaxf(m, x);
            }
            #pragma unroll
            for (int d = 1; d < 16; d <<= 1) m = fmaxf(m, __shfl_xor(m, d, 64));
            float l = 0.f;
            const int row = wm + i * 16 + quad * 4 + r;
            #pragma unroll
            for (int j = 0; j < 4; ++j) {
                const float e = __expf(v[j] - m);   // masked: exp(-3e38-m)=0
                l += e;
                Rs[row * 140 + wn + j * 16 + l15] = f2h(e);
            }
            #pragma unroll
            for (int d = 1; d < 16; d <<= 1) l += __shfl_xor(l, d, 64);
            if (l15 == 0) st[t] = make_float2(m, l);
            // fully-masked subtile: m=NEG_BIG, l=64, P'=1 -- harmless, its
            // pv scale exp(m-M)/L underflows to exactly 0.
        }
    __syncthreads();
    ushort* Pb = Pp + (size_t)b * NT * NT;
    const int g = tid >> 5, cl = tid & 31;
    #pragma unroll
    for (int s = 0; s < 16; ++s) {
        const int row = g * 16 + s;
        const uint2 p = *(const uint2*)&Rs[row * 140 + cl * 4];
        *(uint2*)(Pb + (size_t)(t0b + row) * NT + u0b + cl * 4) = p;
    }
}

// ---------------------------------------------------------------------------
// pv: tile 128(t) x 64(c); heavy t-tiles first; A=P' fp16 (scaled by
// per-(row,subtile) softmax scale from stats), B=V fp16 channel-major.
// LDS-staged main loop (round-6 form): direct-L2 frag reads measured 2x
// SLOWER (round 7: latency-bound at 12% occupancy) -- staging is load-bearing.
// ---------------------------------------------------------------------------
__global__ __launch_bounds__(256, 3) void pv_kernel(
    const ushort* __restrict__ Pp, const float2* __restrict__ stats,
    const ushort* __restrict__ vre, const ushort* __restrict__ vim,
    ushort* __restrict__ Ore, ushort* __restrict__ Oim)
{
    // swizzle: grid (8, 8, 8) = 512, cpx = 64 -> one batch per XCD chunk
    const int swz = xcd_swz(blockIdx.x + 8 * (blockIdx.y + 8 * blockIdx.z), 64);
    const int c0b = (swz & 7) << 6;
    const int t0b = (7 - ((swz >> 3) & 7)) << 7;         // heavy first
    const int b = swz >> 6;
    const int tid = threadIdx.x;
    const ushort* P = Pp + ((size_t)b * NT + t0b) * NT;
    const size_t vb = (size_t)b * NC * NT;
    const int iters = (t0b + 128) >> 6;

    __shared__ alignas(16) ushort SM[20736];             // 40.5 KiB
    ushort* Ps = SM;             // 128*64
    ushort* Vr = SM + 8192;      // 64*64
    ushort* Vi = SM + 12288;     // 64*64
    float* sLds = (float*)(SM + 16384);                  // [128][17]
    uint*  R    = (uint*)SM;                             // repack [128][76]

    float4v acc[2][4][2] = {};

    const int w = tid >> 6, lane = tid & 63;
    const int l15 = lane & 15, quad = lane >> 4;
    const int wm = (w & 1) << 6;
    const int wn = (w >> 1) << 5;

    // prologue: combine subtile stats -> scale_s = exp(m_s - M) / L
    if (tid < 128) {
        const int t = t0b + tid;
        float mv[16], lv[16];
        #pragma unroll
        for (int s = 0; s < 16; ++s) {
            if (s < iters) {
                const float2 v = stats[(size_t)(b * 16 + s) * NT + t];
                mv[s] = v.x; lv[s] = v.y;
            } else { mv[s] = NEG_BIG; lv[s] = 0.f; }
        }
        float M = NEG_BIG;
        #pragma unroll
        for (int s = 0; s < 16; ++s) M = fmaxf(M, mv[s]);
        float L = 0.f; float ev[16];
        #pragma unroll
        for (int s = 0; s < 16; ++s) { ev[s] = __expf(mv[s] - M); L += ev[s] * lv[s]; }
        const float inv = 1.0f / L;
        #pragma unroll
        for (int s = 0; s < 16; ++s) sLds[tid * 17 + s] = ev[s] * inv;
    }
    // visibility of sLds is covered by the first post-stage __syncthreads

    for (int it = 0; it < iters; ++it) {
        const int u0 = it << 6;
        stage64<128>(P + u0, NT, Ps, w, lane);
        stage64<64>(vre + vb + (size_t)c0b * NT + u0, NT, Vr, w, lane);
        stage64<64>(vim + vb + (size_t)c0b * NT + u0, NT, Vi, w, lane);
        __syncthreads();
        #pragma unroll
        for (int kk = 0; kk < 2; ++kk) {
            const int q0 = kk * 4 + quad;
            half8v pf[4], vf[2][2];
            #pragma unroll
            for (int i = 0; i < 4; ++i) {
                const int row = wm + i * 16 + l15;
                pf[i] = scale8(frag(Ps, row, q0), sLds[row * 17 + it]);
            }
            #pragma unroll
            for (int j = 0; j < 2; ++j) {
                vf[0][j] = __builtin_bit_cast(half8v, frag(Vr, wn + j * 16 + l15, q0));
                vf[1][j] = __builtin_bit_cast(half8v, frag(Vi, wn + j * 16 + l15, q0));
            }
            #pragma unroll
            for (int c = 0; c < 2; ++c)
                #pragma unroll
                for (int i = 0; i < 4; ++i)
                    #pragma unroll
                    for (int j = 0; j < 2; ++j)
                        acc[c][i][j] = MFMA_F16(pf[i], vf[c][j], acc[c][i][j]);
        }
        __syncthreads();
    }

    #pragma unroll
    for (int i = 0; i < 4; ++i)
        #pragma unroll
        for (int j = 0; j < 2; ++j)
            #pragma unroll
            for (int r = 0; r < 4; ++r) {
                const int row = wm + i * 16 + quad * 4 + r;   // t-local
                const int col = wn + j * 16 + l15;            // c-local
                R[row * 76 + col] = (uint)f2bf(acc[0][i][j][r])
                                  | ((uint)f2bf(acc[1][i][j][r]) << 16);
            }
    __syncthreads();
    const int g = tid >> 4, cl = tid & 15;
    #pragma unroll
    for (int s = 0; s < 8; ++s) {
        const int row = g * 8 + s;
        const uint4 p = *(const uint4*)&R[row * 76 + cl * 4];
        uint2 re, im;
        re.x = (p.x & 0xFFFFu) | (p.y << 16);
        re.y = (p.z & 0xFFFFu) | (p.w << 16);
        im.x = (p.x >> 16) | (p.y & 0xFFFF0000u);
        im.y = (p.z >> 16) | (p.w & 0xFFFF0000u);
        const size_t off = ((size_t)b * NT + t0b + row) * NC + c0b + cl * 4;
        *(uint2*)(Ore + off) = re;
        *(uint2*)(Oim + off) = im;
    }
}

// ---------------------------------------------------------------------------
// proj_out: tile 128(d) x 64(bt); A=Wo, B=O. fp32 -> d_out [b][d][t].
// Trig by shuffle; LDS-repack (fp32, two rounds) epilogue.
// ---------------------------------------------------------------------------
__global__ __launch_bounds__(256, 3) void proj_out_kernel(
    const ushort* __restrict__ Ore, const ushort* __restrict__ Oim,
    const ushort* __restrict__ Wbf, const float* __restrict__ phio,
    float* __restrict__ outRe, float* __restrict__ outIm)
{
    const int tid = threadIdx.x;
    // swizzle: grid (4, 128) = 512, cpx = 64
    const int swz = xcd_swz(blockIdx.x + 4 * blockIdx.y, 64);
    const int d0 = (swz & 3) << 7;
    const int bt0 = (swz >> 2) << 6;

    __shared__ alignas(16) ushort SM[19456];             // 38 KiB
    ushort* Wo_s = SM;                                   // 128*64
    ushort* Or_s = SM + 8192;                            // 64*64
    ushort* Oi_s = SM + 12288;                           // 64*64
    float*  Rf   = (float*)SM;                           // repack [128][76]

    float4v acc[2][4][2] = {};

    const int w = tid >> 6, lane = tid & 63;
    const int l15 = lane & 15, quad = lane >> 4;
    const int wm = (w & 1) << 6;
    const int wn = (w >> 1) << 5;

    for (int c0 = 0; c0 < NC; c0 += 64) {
        stage64<128>(Wbf + ((size_t)3 << 18) + (size_t)d0 * NC + c0, NC, Wo_s, w, lane);
        stage64<64>(Ore + (size_t)bt0 * NC + c0, NC, Or_s, w, lane);
        stage64<64>(Oim + (size_t)bt0 * NC + c0, NC, Oi_s, w, lane);
        __syncthreads();
        #pragma unroll
        for (int kk = 0; kk < 2; ++kk) {
            const int q0 = kk * 4 + quad;
            short8v wof[4], of[2][2];
            #pragma unroll
            for (int i = 0; i < 4; ++i)
                wof[i] = frag(Wo_s, wm + i * 16 + l15, q0);
            #pragma unroll
            for (int j = 0; j < 2; ++j) {
                of[0][j] = frag(Or_s, wn + j * 16 + l15, q0);
                of[1][j] = frag(Oi_s, wn + j * 16 + l15, q0);
            }
            #pragma unroll
            for (int c = 0; c < 2; ++c)
                #pragma unroll
                for (int i = 0; i < 4; ++i)
                    #pragma unroll
                    for (int j = 0; j < 2; ++j)
                        acc[c][i][j] = MFMA_BF16(wof[i], of[c][j], acc[c][i][j]);
        }
        __syncthreads();
    }

    // trig: one cosf/sinf per lane, shuffled to each (i,r)
    const int d_own = d0 + wm + (l15 >> 2) * 16 + quad * 4 + (l15 & 3);
    const float ph_own = phio[d_own];
    const float c_own = cosf(ph_own), s_own = sinf(ph_own);
    const int g = tid >> 4, cl = tid & 15;
    const int b = bt0 >> 10, t0 = bt0 & 1023;

    // ---- round RE ----
    #pragma unroll
    for (int i = 0; i < 4; ++i)
        #pragma unroll
        for (int r = 0; r < 4; ++r) {
            const int src = (lane & 48) | (i * 4 + r);
            const float cs = __shfl(c_own, src, 64);
            const float sn = __shfl(s_own, src, 64);
            const int row = wm + i * 16 + quad * 4 + r;
            #pragma unroll
            for (int j = 0; j < 2; ++j) {
                const int col = wn + j * 16 + l15;
                Rf[row * 76 + col] = acc[0][i][j][r] * cs - acc[1][i][j][r] * sn;
            }
        }
    __syncthreads();
    #pragma unroll
    for (int s = 0; s < 8; ++s) {
        const int row = g * 8 + s;
        const float4 p = *(const float4*)&Rf[row * 76 + cl * 4];
        *(float4*)(outRe + (size_t)b * NC * NT + (size_t)(d0 + row) * NT + t0 + cl * 4) = p;
    }
    __syncthreads();

    // ---- round IM ----
    #pragma unroll
    for (int i = 0; i < 4; ++i)
        #pragma unroll
        for (int r = 0; r < 4; ++r) {
            const int src = (lane & 48) | (i * 4 + r);
            const float cs = __shfl(c_own, src, 64);
            const float sn = __shfl(s_own, src, 64);
            const int row = wm + i * 16 + quad * 4 + r;
            #pragma unroll
            for (int j = 0; j < 2; ++j) {
                const int col = wn + j * 16 + l15;
                Rf[row * 76 + col] = acc[0][i][j][r] * sn + acc[1][i][j][r] * cs;
            }
        }
    __syncthreads();
    #pragma unroll
    for (int s = 0; s < 8; ++s) {
        const int row = g * 8 + s;
        const float4 p = *(const float4*)&Rf[row * 76 + cl * 4];
        *(float4*)(outIm + (size_t)b * NC * NT + (size_t)(d0 + row) * NT + t0 + cl * 4) = p;
    }
}

extern "C" void kernel_launch(void* const* d_in, const int* in_sizes, int n_in,
                              void* d_out, int out_size, void* d_ws, size_t ws_size,
                              hipStream_t stream) {
    (void)in_sizes; (void)n_in; (void)out_size; (void)ws_size;
    const float* z_re  = (const float*)d_in[0];
    const float* z_im  = (const float*)d_in[1];
    const float* Wq    = (const float*)d_in[2];
    const float* phi_q = (const float*)d_in[3];
    const float* Wk    = (const float*)d_in[4];
    const float* phi_k = (const float*)d_in[5];
    const float* Wv    = (const float*)d_in[6];
    const float* phi_v = (const float*)d_in[7];
    const float* Wo    = (const float*)d_in[8];
    const float* phi_o = (const float*)d_in[9];

    const size_t NE = (size_t)BT * NC;     // 4,194,304
    ushort* ws  = (ushort*)d_ws;
    ushort* qre = ws + 0 * NE; ushort* qim = ws + 1 * NE;   // aliased as O after scores
    ushort* kre = ws + 2 * NE; ushort* kim = ws + 3 * NE;
    ushort* vre = ws + 4 * NE; ushort* vim = ws + 5 * NE;   // channel-major fp16
    ushort* Wbf = ws + 6 * NE;                              // 2 MiB
    // d_out doubles as scratch:
    //   [0      , 16.8MB) : Z bf16 (dead after proj_qk/proj_v) -> stats (1MB)
    //   [16.8MB , 33.5MB) : P' fp16 (written by scores, read by pv)
    // proj_out finally overwrites all of d_out with outRe/outIm.
    ushort* Z  = (ushort*)d_out;
    ushort* Pp = (ushort*)d_out + 2 * NE;
    float2* stats = (float2*)d_out;        // 8 x 16 x 1024 float2 = 1 MiB

    const dim3 blk(256);
    hipLaunchKernelGGL(prep_zw_kernel, dim3(3072), blk, 0, stream,
                       z_re, z_im, Z, Wq, Wk, Wv, Wo, Wbf);
    hipLaunchKernelGGL(proj_qk_kernel, dim3(BT / 128, NC / 64), blk, 0, stream,
                       Z, Wbf, phi_q, phi_k, qre, qim, kre, kim);
    hipLaunchKernelGGL(proj_v_kernel, dim3(NC / 128, BT / 64), blk, 0, stream,
                       Z, Wbf, phi_v, vre, vim);
    hipLaunchKernelGGL(scores_kernel, dim3(NT / 128, NT / 128, NB), blk, 0, stream,
                       qre, qim, kre, kim, Pp, stats);
    hipLaunchKernelGGL(pv_kernel, dim3(NC / 64, NT / 128, NB), blk, 0, stream,
                       Pp, stats, vre, vim, qre, qim);
    hipLaunchKernelGGL(proj_out_kernel, dim3(NC / 128, BT / 64), blk, 0, stream,
                       qre, qim, Wbf, phi_o, (float*)d_out, (float*)d_out + NE);
}

// Round 11
// 188.366 us; speedup vs baseline: 1.2109x; 1.0382x over previous
//
#include <hip/hip_runtime.h>
#include <math.h>

#define NB 8
#define NC 512
#define NT 1024
#define BT (NB * NT)          // 8192 flattened (b,t) rows
#define SCALE 0.125f
#define NEG_BIG (-3.0e38f)

typedef __attribute__((ext_vector_type(8))) short short8v;   // 8 bf16 (A/B frag)
typedef __attribute__((ext_vector_type(8))) _Float16 half8v; // 8 fp16 (A/B frag)
typedef __attribute__((ext_vector_type(4))) float float4v;   // C/D frag
#define MFMA_BF16(A, B, C) __builtin_amdgcn_mfma_f32_16x16x32_bf16(A, B, C, 0, 0, 0)
#define MFMA_F16(A, B, C)  __builtin_amdgcn_mfma_f32_16x16x32_f16(A, B, C, 0, 0, 0)

__device__ __forceinline__ ushort f2bf(float f) {
    union { float f; unsigned int i; } v; v.f = f;
    unsigned int r = v.i + 0x7FFFu + ((v.i >> 16) & 1u);  // RNE
    return (ushort)(r >> 16);
}

__device__ __forceinline__ ushort f2h(float f) {
    return __builtin_bit_cast(unsigned short, (_Float16)f);
}

// P'(fp16, in LDS) * row-scale, producing the f16 MFMA A-frag.
__device__ __forceinline__ half8v scale8(short8v raw, float s) {
    half8v h = __builtin_bit_cast(half8v, raw);
    const _Float16 hs = (_Float16)s;
    half8v r;
    #pragma unroll
    for (int q = 0; q < 8; ++q) r[q] = h[q] * hs;   // v_pk_mul_f16 x4
    return r;
}

#if defined(__has_builtin)
#if __has_builtin(__builtin_amdgcn_global_load_lds)
#define HAS_GLDS 1
#endif
#endif

#ifdef HAS_GLDS
__device__ __forceinline__ void glds16(const ushort* g, ushort* l) {
    __builtin_amdgcn_global_load_lds(
        (const __attribute__((address_space(1))) unsigned int*)g,
        (__attribute__((address_space(3))) unsigned int*)l, 16, 0, 0);
}
#endif

// ---------------------------------------------------------------------------
// BK=64 tile: ROWS x 64 shorts (128B rows). LDS slot p of row r holds global
// 16B-chunk p ^ (r&7)  => every ds_read_b128 frag phase is 2-way (free, m136).
// One issue = 64 lanes x 16B = 8 rows. 4 waves cover ROWS/8 issues.
// ---------------------------------------------------------------------------
template<int ROWS>
__device__ __forceinline__ void stage64(const ushort* __restrict__ g, int rsShorts,
                                        ushort* tile, int w, int lane) {
    const int r8 = lane >> 3;                  // row within 8-row group
    const int ck = (lane & 7) ^ r8;            // global chunk fetched by this lane
    const ushort* gl = g + (size_t)r8 * rsShorts + (ck << 3);
    constexpr int ni = ROWS / 32;              // issues per wave
    #pragma unroll
    for (int s = 0; s < ni; ++s) {
        const int issue = w * ni + s;
#ifdef HAS_GLDS
        glds16(gl + (size_t)issue * 8 * rsShorts, tile + issue * 512);
#else
        const uint4 v = *(const uint4*)(gl + (size_t)issue * 8 * rsShorts);
        *(uint4*)(tile + issue * 512 + lane * 8) = v;
#endif
    }
}

// frag read: row rr (local), chunk q (0..7): swizzled address
__device__ __forceinline__ short8v frag(const ushort* tile, int rr, int q) {
    return *(const short8v*)(tile + rr * 64 + ((q ^ (rr & 7)) << 3));
}

// XCD-chunk swizzle (T1, m157): nwg must be divisible by 8.
// Consecutive logical tiles land on the same XCD -> shared panels stay in L2.
__device__ __forceinline__ int xcd_swz(int flat, int cpx) {
    return (flat & 7) * cpx + (flat >> 3);
}

// ---------------------------------------------------------------------------
// prep_zw: merged prep. Blocks [0,2048): z fp32 [b][c][t] -> Z bf16
// token-major [comp][bt][c]. Blocks [2048,3072): 4x W fp32 -> bf16.
// ---------------------------------------------------------------------------
__global__ __launch_bounds__(256) void prep_zw_kernel(
    const float* __restrict__ zre, const float* __restrict__ zim,
    ushort* __restrict__ Z,
    const float* __restrict__ Wq, const float* __restrict__ Wk,
    const float* __restrict__ Wv, const float* __restrict__ Wo,
    ushort* __restrict__ Wbf)
{
    const int bx = blockIdx.x;
    const int tid = threadIdx.x;
    if (bx >= 2048) {                          // ---- prep_w part ----
        const int idx = (bx - 2048) * 256 + tid;
        const int e4 = idx << 2;
        const int m = e4 >> 18;
        const int off = e4 & ((1 << 18) - 1);
        const float* Ws[4] = {Wq, Wk, Wv, Wo};
        const float4 v = *(const float4*)(Ws[m] + off);
        ushort4 o;
        o.x = f2bf(v.x); o.y = f2bf(v.y); o.z = f2bf(v.z); o.w = f2bf(v.w);
        *(ushort4*)(Wbf + ((size_t)m << 18) + off) = o;
        return;
    }
    // ---- prep_z part ----
    const int t0 = (bx & 15) << 6, c0 = ((bx >> 4) & 7) << 6;
    const int bz = bx >> 7, b = bz & 7, comp = bz >> 3;
    const float* src = (comp ? zim : zre) + (size_t)b * NC * NT;
    ushort* dst = Z + (size_t)(comp * NB + b) * NT * NC;

    __shared__ ushort T[64][72];
    #pragma unroll
    for (int r = 0; r < 4; ++r) {
        const int cl = (tid >> 4) + r * 16;
        const int t4 = (tid & 15) << 2;
        const float4 v = *(const float4*)(src + (size_t)(c0 + cl) * NT + t0 + t4);
        T[t4 + 0][cl] = f2bf(v.x); T[t4 + 1][cl] = f2bf(v.y);
        T[t4 + 2][cl] = f2bf(v.z); T[t4 + 3][cl] = f2bf(v.w);
    }
    __syncthreads();
    const int tl = tid >> 2, cc = (tid & 3) << 4;
    ushort* op = dst + (size_t)(t0 + tl) * NC + c0 + cc;
    *(uint4*)op       = *(const uint4*)&T[tl][cc];
    *(uint4*)(op + 8) = *(const uint4*)&T[tl][cc + 8];
}

// ---------------------------------------------------------------------------
// proj_qk: tile 128(bt) x 64(d); wave 64x32 computes q AND k, re+im.
// XCD chunk = {8 m-tiles x all 8 d-bands}, d-fastest: Wq/Wk (1MB) L2-resident,
// each Z m-tile (0.5MB) fetched once, reused 8x from L2.
// launch_bounds(256,2): (256,3) forced VGPR to 84 < 128 acc floats -> spill
// (round 9: 130us dispatch). 2 blocks/CU is the correct occupancy here.
// Epilogue: LDS repack (re|im u32, stride 76) -> coalesced uint2 stores.
// ---------------------------------------------------------------------------
__global__ __launch_bounds__(256, 2) void proj_qk_kernel(
    const ushort* __restrict__ Z, const ushort* __restrict__ Wbf,
    const float* __restrict__ phiq, const float* __restrict__ phik,
    ushort* __restrict__ qre, ushort* __restrict__ qim,
    ushort* __restrict__ kre, ushort* __restrict__ kim)
{
    const int tid = threadIdx.x;
    // swizzle: grid (64, 8) = 512, cpx = 64; within chunk d0 fastest
    const int swz = xcd_swz(blockIdx.x + 64 * blockIdx.y, 64);
    const int d0 = (swz & 7) << 6;
    const int m0 = (swz >> 3) << 7;
    const size_t NE = (size_t)BT * NC;

    __shared__ alignas(16) ushort SM[24576];             // 48 KiB
    ushort* Zr   = SM;                                   // 128*64
    ushort* Zi   = SM + 8192;                            // 128*64
    ushort* Wq_s = SM + 16384;                           // 64*64
    ushort* Wk_s = SM + 20480;                           // 64*64
    uint*   R    = (uint*)SM;                            // repack [128][76]

    float4v accq[2][4][2] = {};
    float4v acck[2][4][2] = {};

    const int w = tid >> 6, lane = tid & 63;
    const int l15 = lane & 15, quad = lane >> 4;
    const int wm = (w & 1) << 6;
    const int wn = (w >> 1) << 5;

    for (int c0 = 0; c0 < NC; c0 += 64) {
        stage64<128>(Z + (size_t)m0 * NC + c0, NC, Zr, w, lane);
        stage64<128>(Z + NE + (size_t)m0 * NC + c0, NC, Zi, w, lane);
        stage64<64>(Wbf + (size_t)d0 * NC + c0, NC, Wq_s, w, lane);
        stage64<64>(Wbf + ((size_t)1 << 18) + (size_t)d0 * NC + c0, NC, Wk_s, w, lane);
        __syncthreads();
        #pragma unroll
        for (int kk = 0; kk < 2; ++kk) {
            const int q0 = kk * 4 + quad;
            short8v zf[2][4], wqf[2], wkf[2];
            #pragma unroll
            for (int i = 0; i < 4; ++i) {
                zf[0][i] = frag(Zr, wm + i * 16 + l15, q0);
                zf[1][i] = frag(Zi, wm + i * 16 + l15, q0);
            }
            #pragma unroll
            for (int j = 0; j < 2; ++j) {
                wqf[j] = frag(Wq_s, wn + j * 16 + l15, q0);
                wkf[j] = frag(Wk_s, wn + j * 16 + l15, q0);
            }
            #pragma unroll
            for (int c = 0; c < 2; ++c)
                #pragma unroll
                for (int i = 0; i < 4; ++i)
                    #pragma unroll
                    for (int j = 0; j < 2; ++j) {
                        accq[c][i][j] = MFMA_BF16(zf[c][i], wqf[j], accq[c][i][j]);
                        acck[c][i][j] = MFMA_BF16(zf[c][i], wkf[j], acck[c][i][j]);
                    }
        }
        __syncthreads();
    }

    // trig per j (2 d's per lane)
    float cq[2], sq[2], ck2[2], sk2[2];
    #pragma unroll
    for (int j = 0; j < 2; ++j) {
        const int d = d0 + wn + j * 16 + l15;
        const float pq = phiq[d], pk = phik[d];
        cq[j] = cosf(pq); sq[j] = sinf(pq);
        ck2[j] = cosf(pk); sk2[j] = sinf(pk);
    }
    const int g = tid >> 4, cl = tid & 15;

    // ---- round Q ----
    #pragma unroll
    for (int j = 0; j < 2; ++j)
        #pragma unroll
        for (int i = 0; i < 4; ++i)
            #pragma unroll
            for (int r = 0; r < 4; ++r) {
                const int row = wm + i * 16 + quad * 4 + r;
                const int col = wn + j * 16 + l15;
                const float ar = accq[0][i][j][r], ai = accq[1][i][j][r];
                R[row * 76 + col] = (uint)f2bf(ar * cq[j] - ai * sq[j])
                                  | ((uint)f2bf(ar * sq[j] + ai * cq[j]) << 16);
            }
    __syncthreads();
    #pragma unroll
    for (int s = 0; s < 8; ++s) {
        const int row = g * 8 + s;
        const uint4 p = *(const uint4*)&R[row * 76 + cl * 4];
        uint2 re, im;
        re.x = (p.x & 0xFFFFu) | (p.y << 16);
        re.y = (p.z & 0xFFFFu) | (p.w << 16);
        im.x = (p.x >> 16) | (p.y & 0xFFFF0000u);
        im.y = (p.z >> 16) | (p.w & 0xFFFF0000u);
        const size_t off = (size_t)(m0 + row) * NC + d0 + cl * 4;
        *(uint2*)(qre + off) = re;
        *(uint2*)(qim + off) = im;
    }
    __syncthreads();

    // ---- round K ----
    #pragma unroll
    for (int j = 0; j < 2; ++j)
        #pragma unroll
        for (int i = 0; i < 4; ++i)
            #pragma unroll
            for (int r = 0; r < 4; ++r) {
                const int row = wm + i * 16 + quad * 4 + r;
                const int col = wn + j * 16 + l15;
                const float br = acck[0][i][j][r], bi = acck[1][i][j][r];
                R[row * 76 + col] = (uint)f2bf(br * ck2[j] - bi * sk2[j])
                                  | ((uint)f2bf(br * sk2[j] + bi * ck2[j]) << 16);
            }
    __syncthreads();
    #pragma unroll
    for (int s = 0; s < 8; ++s) {
        const int row = g * 8 + s;
        const uint4 p = *(const uint4*)&R[row * 76 + cl * 4];
        uint2 re, im;
        re.x = (p.x & 0xFFFFu) | (p.y << 16);
        re.y = (p.z & 0xFFFFu) | (p.w << 16);
        im.x = (p.x >> 16) | (p.y & 0xFFFF0000u);
        im.y = (p.z >> 16) | (p.w & 0xFFFF0000u);
        const size_t off = (size_t)(m0 + row) * NC + d0 + cl * 4;
        *(uint2*)(kre + off) = re;
        *(uint2*)(kim + off) = im;
    }
}

// ---------------------------------------------------------------------------
// proj_v: tile 128(d) x 64(bt); A=Wv, B=Z -> channel-major v, re+im (FP16).
// Trig by shuffle; LDS-repack epilogue. Chunk order d-fastest.
// ---------------------------------------------------------------------------
__global__ __launch_bounds__(256, 3) void proj_v_kernel(
    const ushort* __restrict__ Z, const ushort* __restrict__ Wbf,
    const float* __restrict__ phiv,
    ushort* __restrict__ vre, ushort* __restrict__ vim)
{
    const int tid = threadIdx.x;
    // swizzle: grid (4, 128) = 512, cpx = 64
    const int swz = xcd_swz(blockIdx.x + 4 * blockIdx.y, 64);
    const int d0 = (swz & 3) << 7;
    const int bt0 = (swz >> 2) << 6;
    const size_t NE = (size_t)BT * NC;

    __shared__ alignas(16) ushort SM[19456];             // 38 KiB
    ushort* Wv_s = SM;                                   // 128*64
    ushort* Zr   = SM + 8192;                            // 64*64
    ushort* Zi   = SM + 12288;                           // 64*64
    uint*   R    = (uint*)SM;                            // repack [128][76]

    float4v acc[2][4][2] = {};

    const int w = tid >> 6, lane = tid & 63;
    const int l15 = lane & 15, quad = lane >> 4;
    const int wm = (w & 1) << 6;
    const int wn = (w >> 1) << 5;

    for (int c0 = 0; c0 < NC; c0 += 64) {
        stage64<128>(Wbf + ((size_t)2 << 18) + (size_t)d0 * NC + c0, NC, Wv_s, w, lane);
        stage64<64>(Z + (size_t)bt0 * NC + c0, NC, Zr, w, lane);
        stage64<64>(Z + NE + (size_t)bt0 * NC + c0, NC, Zi, w, lane);
        __syncthreads();
        #pragma unroll
        for (int kk = 0; kk < 2; ++kk) {
            const int q0 = kk * 4 + quad;
            short8v wvf[4], zf[2][2];
            #pragma unroll
            for (int i = 0; i < 4; ++i)
                wvf[i] = frag(Wv_s, wm + i * 16 + l15, q0);
            #pragma unroll
            for (int j = 0; j < 2; ++j) {
                zf[0][j] = frag(Zr, wn + j * 16 + l15, q0);
                zf[1][j] = frag(Zi, wn + j * 16 + l15, q0);
            }
            #pragma unroll
            for (int c = 0; c < 2; ++c)
                #pragma unroll
                for (int i = 0; i < 4; ++i)
                    #pragma unroll
                    for (int j = 0; j < 2; ++j)
                        acc[c][i][j] = MFMA_BF16(wvf[i], zf[c][j], acc[c][i][j]);
        }
        __syncthreads();
    }

    // trig: lane computes its own (i,r)=(l15>>2,l15&3), shuffle to distribute
    const int d_own = d0 + wm + (l15 >> 2) * 16 + quad * 4 + (l15 & 3);
    const float ph_own = phiv[d_own];
    const float c_own = cosf(ph_own), s_own = sinf(ph_own);

    #pragma unroll
    for (int i = 0; i < 4; ++i)
        #pragma unroll
        for (int r = 0; r < 4; ++r) {
            const int src = (lane & 48) | (i * 4 + r);
            const float cs = __shfl(c_own, src, 64);
            const float sn = __shfl(s_own, src, 64);
            const int row = wm + i * 16 + quad * 4 + r;      // d-local
            #pragma unroll
            for (int j = 0; j < 2; ++j) {
                const int col = wn + j * 16 + l15;           // t-local
                const float vr = acc[0][i][j][r], vi = acc[1][i][j][r];
                R[row * 76 + col] = (uint)f2h(vr * cs - vi * sn)
                                  | ((uint)f2h(vr * sn + vi * cs) << 16);
            }
        }
    __syncthreads();
    const int g = tid >> 4, cl = tid & 15;
    const int b = bt0 >> 10, t0 = bt0 & 1023;
    #pragma unroll
    for (int s = 0; s < 8; ++s) {
        const int row = g * 8 + s;
        const uint4 p = *(const uint4*)&R[row * 76 + cl * 4];
        uint2 re, im;
        re.x = (p.x & 0xFFFFu) | (p.y << 16);
        re.y = (p.z & 0xFFFFu) | (p.w << 16);
        im.x = (p.x >> 16) | (p.y & 0xFFFF0000u);
        im.y = (p.z >> 16) | (p.w & 0xFFFF0000u);
        const size_t off = (size_t)b * NC * NT + (size_t)(d0 + row) * NT + t0 + cl * 4;
        *(uint2*)(vre + off) = re;
        *(uint2*)(vim + off) = im;
    }
}

// ---------------------------------------------------------------------------
// scores: tile 128(t) x 128(u); heavy t-tiles first. 2-PHASE DOUBLE-BUFFERED
// re/im phase-split: 16 steps x 32KB staging quantum, two 32KB buffers, ONE
// barrier per step; next step's global_load_lds issued BEFORE compute so its
// L2 latency hides under 32 MFMA (T3 minimum-2-phase; same 2 blocks/CU).
// Fused per-64u-subtile softmax -> P' fp16 via LDS repack + (m,l) stats.
// batch b pinned to XCD b (swizzle) => P'/stats stay in that XCD's L2 for pv.
// ---------------------------------------------------------------------------
__global__ __launch_bounds__(256, 2) void scores_kernel(
    const ushort* __restrict__ qre, const ushort* __restrict__ qim,
    const ushort* __restrict__ kre, const ushort* __restrict__ kim,
    ushort* __restrict__ Pp, float2* __restrict__ stats)
{
    // swizzle: grid (8, 8, 8) = 512, cpx = 64 -> one batch per XCD chunk
    const int swz = xcd_swz(blockIdx.x + 8 * (blockIdx.y + 8 * blockIdx.z), 64);
    const int u0b = (swz & 7) << 7;
    const int t0b = (7 - ((swz >> 3) & 7)) << 7;         // heavy first
    if (u0b > t0b) return;
    const int b = swz >> 6;
    const int tid = threadIdx.x;
    const size_t qb = (size_t)b * NT * NC;

    __shared__ alignas(16) ushort SM[32768];             // 64 KiB = 2 x 32KB buf
    // buffer p at SM + p*16384: Q tile +0 (128x64), K tile +8192 (128x64)
    ushort* Rs = SM;             // repack [128][140] shorts = 35840B (aliased)

    float4v acc[4][4] = {};

    const int w = tid >> 6, lane = tid & 63;
    const int l15 = lane & 15, quad = lane >> 4;
    const int wm = (w & 1) << 6;
    const int wn = (w >> 1) << 6;

    // prologue: stage step 0 (re, c0=0)
    stage64<128>(qre + qb + (size_t)t0b * NC, NC, SM, w, lane);
    stage64<128>(kre + qb + (size_t)u0b * NC, NC, SM + 8192, w, lane);
    __syncthreads();

    for (int s = 0; s < 16; ++s) {
        const int cur = (s & 1) << 14;                   // ushort offset 0/16384
        const int nxt = cur ^ 16384;
        if (s + 1 < 16) {                                // issue next stage NOW
            const int c0n = ((s + 1) >> 1) << 6;
            const ushort* qs = ((s + 1) & 1 ? qim : qre) + qb + (size_t)t0b * NC + c0n;
            const ushort* ks = ((s + 1) & 1 ? kim : kre) + qb + (size_t)u0b * NC + c0n;
            stage64<128>(qs, NC, SM + nxt, w, lane);
            stage64<128>(ks, NC, SM + nxt + 8192, w, lane);
        }
        const ushort* Qs = SM + cur;
        const ushort* Ks = SM + cur + 8192;
        #pragma unroll
        for (int kk = 0; kk < 2; ++kk) {
            const int q0 = kk * 4 + quad;
            short8v qf[4], kf[4];
            #pragma unroll
            for (int i = 0; i < 4; ++i) {
                qf[i] = frag(Qs, wm + i * 16 + l15, q0);
                kf[i] = frag(Ks, wn + i * 16 + l15, q0);
            }
            #pragma unroll
            for (int i = 0; i < 4; ++i)
                #pragma unroll
                for (int j = 0; j < 4; ++j)
                    acc[i][j] = MFMA_BF16(qf[i], kf[j], acc[i][j]);
        }
        __syncthreads();                                 // next buf ready, cur consumed
    }

    // ---- fused per-64u-subtile softmax stats + P' into LDS repack ----
    const int sub = (u0b + wn) >> 6;            // global 64u-subtile index
    float2* st = stats + (size_t)(b * 16 + sub) * NT;
    #pragma unroll
    for (int i = 0; i < 4; ++i)
        #pragma unroll
        for (int r = 0; r < 4; ++r) {
            const int t = t0b + wm + i * 16 + quad * 4 + r;
            float v[4]; float m = NEG_BIG;
            #pragma unroll
            for (int j = 0; j < 4; ++j) {
                const int u = u0b + wn + j * 16 + l15;
                const float x = (u > t) ? NEG_BIG : acc[i][j][r] * SCALE;
                v[j] = x; m = fmaxf(m, x);
            }
            #pragma unroll
            for (int d = 1; d < 16; d <<= 1) m = fmaxf(m, __shfl_xor(m, d, 64));
            float l = 0.f;
            const int row = wm + i * 16 + quad * 4 + r;
            #pragma unroll
            for (int j = 0; j < 4; ++j) {
                const float e = __expf(v[j] - m);   // masked: exp(-3e38-m)=0
                l += e;
                Rs[row * 140 + wn + j * 16 + l15] = f2h(e);
            }
            #pragma unroll
            for (int d = 1; d < 16; d <<= 1) l += __shfl_xor(l, d, 64);
            if (l15 == 0) st[t] = make_float2(m, l);
            // fully-masked subtile: m=NEG_BIG, l=64, P'=1 -- harmless, its
            // pv scale exp(m-M)/L underflows to exactly 0.
        }
    __syncthreads();
    ushort* Pb = Pp + (size_t)b * NT * NT;
    const int g = tid >> 5, cl = tid & 31;
    #pragma unroll
    for (int s = 0; s < 16; ++s) {
        const int row = g * 16 + s;
        const uint2 p = *(const uint2*)&Rs[row * 140 + cl * 4];
        *(uint2*)(Pb + (size_t)(t0b + row) * NT + u0b + cl * 4) = p;
    }
}

// ---------------------------------------------------------------------------
// pv: tile 128(t) x 64(c); heavy t-tiles first; A=P' fp16 (scaled by
// per-(row,subtile) softmax scale from stats), B=V fp16 channel-major.
// 2-PHASE DOUBLE-BUFFERED: 32KB/iter quantum, two buffers (64KB) + sLds
// (8.5KB) = 72.5KB -> 2 blocks/CU; one barrier per iter, staging latency
// hides under MFMA (T3). Direct-L2 reads measured 2x slower (round 7).
// ---------------------------------------------------------------------------
__global__ __launch_bounds__(256, 2) void pv_kernel(
    const ushort* __restrict__ Pp, const float2* __restrict__ stats,
    const ushort* __restrict__ vre, const ushort* __restrict__ vim,
    ushort* __restrict__ Ore, ushort* __restrict__ Oim)
{
    // swizzle: grid (8, 8, 8) = 512, cpx = 64 -> one batch per XCD chunk
    const int swz = xcd_swz(blockIdx.x + 8 * (blockIdx.y + 8 * blockIdx.z), 64);
    const int c0b = (swz & 7) << 6;
    const int t0b = (7 - ((swz >> 3) & 7)) << 7;         // heavy first
    const int b = swz >> 6;
    const int tid = threadIdx.x;
    const ushort* P = Pp + ((size_t)b * NT + t0b) * NT;
    const size_t vb = (size_t)b * NC * NT;
    const int iters = (t0b + 128) >> 6;

    __shared__ alignas(16) ushort SM[37120];   // 2x32KB buf + 8.5KB sLds
    // buffer p at SM + p*16384: Ps +0 (128x64), Vr +8192 (64x64), Vi +12288
    float* sLds = (float*)(SM + 32768);                  // [128][17]
    uint*  R    = (uint*)SM;                             // repack [128][76]

    float4v acc[2][4][2] = {};

    const int w = tid >> 6, lane = tid & 63;
    const int l15 = lane & 15, quad = lane >> 4;
    const int wm = (w & 1) << 6;
    const int wn = (w >> 1) << 5;

    // prologue: stage iter 0 + combine subtile stats -> scale = exp(m_s-M)/L
    stage64<128>(P, NT, SM, w, lane);
    stage64<64>(vre + vb + (size_t)c0b * NT, NT, SM + 8192, w, lane);
    stage64<64>(vim + vb + (size_t)c0b * NT, NT, SM + 12288, w, lane);
    if (tid < 128) {
        const int t = t0b + tid;
        float mv[16], lv[16];
        #pragma unroll
        for (int s = 0; s < 16; ++s) {
            if (s < iters) {
                const float2 v = stats[(size_t)(b * 16 + s) * NT + t];
                mv[s] = v.x; lv[s] = v.y;
            } else { mv[s] = NEG_BIG; lv[s] = 0.f; }
        }
        float M = NEG_BIG;
        #pragma unroll
        for (int s = 0; s < 16; ++s) M = fmaxf(M, mv[s]);
        float L = 0.f; float ev[16];
        #pragma unroll
        for (int s = 0; s < 16; ++s) { ev[s] = __expf(mv[s] - M); L += ev[s] * lv[s]; }
        const float inv = 1.0f / L;
        #pragma unroll
        for (int s = 0; s < 16; ++s) sLds[tid * 17 + s] = ev[s] * inv;
    }
    __syncthreads();                                     // buf0 + sLds ready

    for (int it = 0; it < iters; ++it) {
        const int cur = (it & 1) << 14;
        const int nxt = cur ^ 16384;
        if (it + 1 < iters) {                            // issue next stage NOW
            const int u0 = (it + 1) << 6;
            stage64<128>(P + u0, NT, SM + nxt, w, lane);
            stage64<64>(vre + vb + (size_t)c0b * NT + u0, NT, SM + nxt + 8192, w, lane);
            stage64<64>(vim + vb + (size_t)c0b * NT + u0, NT, SM + nxt + 12288, w, lane);
        }
        const ushort* Ps = SM + cur;
        const ushort* Vr = SM + cur + 8192;
        const ushort* Vi = SM + cur + 12288;
        #pragma unroll
        for (int kk = 0; kk < 2; ++kk) {
            const int q0 = kk * 4 + quad;
            half8v pf[4], vf[2][2];
            #pragma unroll
            for (int i = 0; i < 4; ++i) {
                const int row = wm + i * 16 + l15;
                pf[i] = scale8(frag(Ps, row, q0), sLds[row * 17 + it]);
            }
            #pragma unroll
            for (int j = 0; j < 2; ++j) {
                vf[0][j] = __builtin_bit_cast(half8v, frag(Vr, wn + j * 16 + l15, q0));
                vf[1][j] = __builtin_bit_cast(half8v, frag(Vi, wn + j * 16 + l15, q0));
            }
            #pragma unroll
            for (int c = 0; c < 2; ++c)
                #pragma unroll
                for (int i = 0; i < 4; ++i)
                    #pragma unroll
                    for (int j = 0; j < 2; ++j)
                        acc[c][i][j] = MFMA_F16(pf[i], vf[c][j], acc[c][i][j]);
        }
        __syncthreads();                                 // next buf ready
    }

    #pragma unroll
    for (int i = 0; i < 4; ++i)
        #pragma unroll
        for (int j = 0; j < 2; ++j)
            #pragma unroll
            for (int r = 0; r < 4; ++r) {
                const int row = wm + i * 16 + quad * 4 + r;   // t-local
                const int col = wn + j * 16 + l15;            // c-local
                R[row * 76 + col] = (uint)f2bf(acc[0][i][j][r])
                                  | ((uint)f2bf(acc[1][i][j][r]) << 16);
            }
    __syncthreads();
    const int g = tid >> 4, cl = tid & 15;
    #pragma unroll
    for (int s = 0; s < 8; ++s) {
        const int row = g * 8 + s;
        const uint4 p = *(const uint4*)&R[row * 76 + cl * 4];
        uint2 re, im;
        re.x = (p.x & 0xFFFFu) | (p.y << 16);
        re.y = (p.z & 0xFFFFu) | (p.w << 16);
        im.x = (p.x >> 16) | (p.y & 0xFFFF0000u);
        im.y = (p.z >> 16) | (p.w & 0xFFFF0000u);
        const size_t off = ((size_t)b * NT + t0b + row) * NC + c0b + cl * 4;
        *(uint2*)(Ore + off) = re;
        *(uint2*)(Oim + off) = im;
    }
}

// ---------------------------------------------------------------------------
// proj_out: tile 128(d) x 64(bt); A=Wo, B=O. fp32 -> d_out [b][d][t].
// Trig by shuffle; LDS-repack (fp32, two rounds) epilogue.
// ---------------------------------------------------------------------------
__global__ __launch_bounds__(256, 3) void proj_out_kernel(
    const ushort* __restrict__ Ore, const ushort* __restrict__ Oim,
    const ushort* __restrict__ Wbf, const float* __restrict__ phio,
    float* __restrict__ outRe, float* __restrict__ outIm)
{
    const int tid = threadIdx.x;
    // swizzle: grid (4, 128) = 512, cpx = 64
    const int swz = xcd_swz(blockIdx.x + 4 * blockIdx.y, 64);
    const int d0 = (swz & 3) << 7;
    const int bt0 = (swz >> 2) << 6;

    __shared__ alignas(16) ushort SM[19456];             // 38 KiB
    ushort* Wo_s = SM;                                   // 128*64
    ushort* Or_s = SM + 8192;                            // 64*64
    ushort* Oi_s = SM + 12288;                           // 64*64
    float*  Rf   = (float*)SM;                           // repack [128][76]

    float4v acc[2][4][2] = {};

    const int w = tid >> 6, lane = tid & 63;
    const int l15 = lane & 15, quad = lane >> 4;
    const int wm = (w & 1) << 6;
    const int wn = (w >> 1) << 5;

    for (int c0 = 0; c0 < NC; c0 += 64) {
        stage64<128>(Wbf + ((size_t)3 << 18) + (size_t)d0 * NC + c0, NC, Wo_s, w, lane);
        stage64<64>(Ore + (size_t)bt0 * NC + c0, NC, Or_s, w, lane);
        stage64<64>(Oim + (size_t)bt0 * NC + c0, NC, Oi_s, w, lane);
        __syncthreads();
        #pragma unroll
        for (int kk = 0; kk < 2; ++kk) {
            const int q0 = kk * 4 + quad;
            short8v wof[4], of[2][2];
            #pragma unroll
            for (int i = 0; i < 4; ++i)
                wof[i] = frag(Wo_s, wm + i * 16 + l15, q0);
            #pragma unroll
            for (int j = 0; j < 2; ++j) {
                of[0][j] = frag(Or_s, wn + j * 16 + l15, q0);
                of[1][j] = frag(Oi_s, wn + j * 16 + l15, q0);
            }
            #pragma unroll
            for (int c = 0; c < 2; ++c)
                #pragma unroll
                for (int i = 0; i < 4; ++i)
                    #pragma unroll
                    for (int j = 0; j < 2; ++j)
                        acc[c][i][j] = MFMA_BF16(wof[i], of[c][j], acc[c][i][j]);
        }
        __syncthreads();
    }

    // trig: one cosf/sinf per lane, shuffled to each (i,r)
    const int d_own = d0 + wm + (l15 >> 2) * 16 + quad * 4 + (l15 & 3);
    const float ph_own = phio[d_own];
    const float c_own = cosf(ph_own), s_own = sinf(ph_own);
    const int g = tid >> 4, cl = tid & 15;
    const int b = bt0 >> 10, t0 = bt0 & 1023;

    // ---- round RE ----
    #pragma unroll
    for (int i = 0; i < 4; ++i)
        #pragma unroll
        for (int r = 0; r < 4; ++r) {
            const int src = (lane & 48) | (i * 4 + r);
            const float cs = __shfl(c_own, src, 64);
            const float sn = __shfl(s_own, src, 64);
            const int row = wm + i * 16 + quad * 4 + r;
            #pragma unroll
            for (int j = 0; j < 2; ++j) {
                const int col = wn + j * 16 + l15;
                Rf[row * 76 + col] = acc[0][i][j][r] * cs - acc[1][i][j][r] * sn;
            }
        }
    __syncthreads();
    #pragma unroll
    for (int s = 0; s < 8; ++s) {
        const int row = g * 8 + s;
        const float4 p = *(const float4*)&Rf[row * 76 + cl * 4];
        *(float4*)(outRe + (size_t)b * NC * NT + (size_t)(d0 + row) * NT + t0 + cl * 4) = p;
    }
    __syncthreads();

    // ---- round IM ----
    #pragma unroll
    for (int i = 0; i < 4; ++i)
        #pragma unroll
        for (int r = 0; r < 4; ++r) {
            const int src = (lane & 48) | (i * 4 + r);
            const float cs = __shfl(c_own, src, 64);
            const float sn = __shfl(s_own, src, 64);
            const int row = wm + i * 16 + quad * 4 + r;
            #pragma unroll
            for (int j = 0; j < 2; ++j) {
                const int col = wn + j * 16 + l15;
                Rf[row * 76 + col] = acc[0][i][j][r] * sn + acc[1][i][j][r] * cs;
            }
        }
    __syncthreads();
    #pragma unroll
    for (int s = 0; s < 8; ++s) {
        const int row = g * 8 + s;
        const float4 p = *(const float4*)&Rf[row * 76 + cl * 4];
        *(float4*)(outIm + (size_t)b * NC * NT + (size_t)(d0 + row) * NT + t0 + cl * 4) = p;
    }
}

extern "C" void kernel_launch(void* const* d_in, const int* in_sizes, int n_in,
                              void* d_out, int out_size, void* d_ws, size_t ws_size,
                              hipStream_t stream) {
    (void)in_sizes; (void)n_in; (void)out_size; (void)ws_size;
    const float* z_re  = (const float*)d_in[0];
    const float* z_im  = (const float*)d_in[1];
    const float* Wq    = (const float*)d_in[2];
    const float* phi_q = (const float*)d_in[3];
    const float* Wk    = (const float*)d_in[4];
    const float* phi_k = (const float*)d_in[5];
    const float* Wv    = (const float*)d_in[6];
    const float* phi_v = (const float*)d_in[7];
    const float* Wo    = (const float*)d_in[8];
    const float* phi_o = (const float*)d_in[9];

    const size_t NE = (size_t)BT * NC;     // 4,194,304
    ushort* ws  = (ushort*)d_ws;
    ushort* qre = ws + 0 * NE; ushort* qim = ws + 1 * NE;   // aliased as O after scores
    ushort* kre = ws + 2 * NE; ushort* kim = ws + 3 * NE;
    ushort* vre = ws + 4 * NE; ushort* vim = ws + 5 * NE;   // channel-major fp16
    ushort* Wbf = ws + 6 * NE;                              // 2 MiB
    // d_out doubles as scratch:
    //   [0      , 16.8MB) : Z bf16 (dead after proj_qk/proj_v) -> stats (1MB)
    //   [16.8MB , 33.5MB) : P' fp16 (written by scores, read by pv)
    // proj_out finally overwrites all of d_out with outRe/outIm.
    ushort* Z  = (ushort*)d_out;
    ushort* Pp = (ushort*)d_out + 2 * NE;
    float2* stats = (float2*)d_out;        // 8 x 16 x 1024 float2 = 1 MiB

    const dim3 blk(256);
    hipLaunchKernelGGL(prep_zw_kernel, dim3(3072), blk, 0, stream,
                       z_re, z_im, Z, Wq, Wk, Wv, Wo, Wbf);
    hipLaunchKernelGGL(proj_qk_kernel, dim3(BT / 128, NC / 64), blk, 0, stream,
                       Z, Wbf, phi_q, phi_k, qre, qim, kre, kim);
    hipLaunchKernelGGL(proj_v_kernel, dim3(NC / 128, BT / 64), blk, 0, stream,
                       Z, Wbf, phi_v, vre, vim);
    hipLaunchKernelGGL(scores_kernel, dim3(NT / 128, NT / 128, NB), blk, 0, stream,
                       qre, qim, kre, kim, Pp, stats);
    hipLaunchKernelGGL(pv_kernel, dim3(NC / 64, NT / 128, NB), blk, 0, stream,
                       Pp, stats, vre, vim, qre, qim);
    hipLaunchKernelGGL(proj_out_kernel, dim3(NC / 128, BT / 64), blk, 0, stream,
                       qre, qim, Wbf, phi_o, (float*)d_out, (float*)d_out + NE);
}